// Round 1
// baseline (1782.697 us; speedup 1.0000x reference)
//
#include <hip/hip_runtime.h>
#include <stdint.h>

#define HH 512
#define WW 512
#define HW 262144
#define CH 64
#define HID 256

__device__ __forceinline__ float bf2f(uint16_t u) {
    return __uint_as_float(((uint32_t)u) << 16);
}
__device__ __forceinline__ uint16_t f2bf(float f) {
    uint32_t x = __float_as_uint(f);
    uint32_t r = x + 0x7fffu + ((x >> 16) & 1u);
    return (uint16_t)(r >> 16);
}

// ws float layout (after s1 + h byte regions):
// qw 2048 | qb 32 | kw 2048 | kb 32 | vw 4096 | vb 64   (=8320)
// f1w [c][256] 16384 | f1b 256                           (=24960)
// f2w [c][64] 16384  | f2b 64                            (=41408 floats)

__global__ __launch_bounds__(256) void k0_fold(
    const float* __restrict__ q_w, const float* __restrict__ q_b,
    const float* __restrict__ k_w, const float* __restrict__ k_b,
    const float* __restrict__ v_w, const float* __restrict__ v_b,
    const float* __restrict__ bn1_g, const float* __restrict__ bn1_b,
    const float* __restrict__ bn1_m, const float* __restrict__ bn1_v,
    const float* __restrict__ fc1_w, const float* __restrict__ fc1_b,
    const float* __restrict__ bn2_g, const float* __restrict__ bn2_b,
    const float* __restrict__ bn2_m, const float* __restrict__ bn2_v,
    const float* __restrict__ fc2_w, const float* __restrict__ fc2_b,
    const float* __restrict__ dw_b,
    const float* __restrict__ bn3_g, const float* __restrict__ bn3_b,
    const float* __restrict__ bn3_m, const float* __restrict__ bn3_v,
    float* __restrict__ wsw)
{
    __shared__ float s1s[64], t1s[64], s2s[64], t2s[64], s3s[256], t3s[256];
    int tid = threadIdx.x;
    if (tid < 64) {
        float s = bn1_g[tid] * rsqrtf(bn1_v[tid] + 1e-5f);
        s1s[tid] = s; t1s[tid] = bn1_b[tid] - bn1_m[tid] * s;
        float s2 = bn2_g[tid] * rsqrtf(bn2_v[tid] + 1e-5f);
        s2s[tid] = s2; t2s[tid] = bn2_b[tid] - bn2_m[tid] * s2;
    }
    if (tid < 256) {
        float s = bn3_g[tid] * rsqrtf(bn3_v[tid] + 1e-5f);
        s3s[tid] = s;
        t3s[tid] = (dw_b[tid] - bn3_m[tid]) * s + bn3_b[tid];
    }
    __syncthreads();
    float* qw = wsw;
    float* qb = qw + 2048;
    float* kw = qb + 32;
    float* kb = kw + 2048;
    float* vw = kb + 32;
    float* vb = vw + 4096;
    float* f1w = vb + 64;
    float* f1b = f1w + 16384;
    float* f2w = f1b + 256;
    float* f2b = f2w + 16384;

    for (int i = tid; i < 2048; i += 256) {
        int c = i & 63;
        qw[i] = q_w[i] * s1s[c];
        kw[i] = k_w[i] * s1s[c];
    }
    for (int i = tid; i < 4096; i += 256) {
        int c = i & 63;
        vw[i] = v_w[i] * s1s[c];
    }
    if (tid < 32) {
        float a = q_b[tid], b = k_b[tid];
        for (int c = 0; c < 64; c++) { a += q_w[tid*64+c]*t1s[c]; b += k_w[tid*64+c]*t1s[c]; }
        qb[tid] = a; kb[tid] = b;
    }
    if (tid >= 64 && tid < 128) {
        int o = tid - 64;
        float a = v_b[o];
        for (int c = 0; c < 64; c++) a += v_w[o*64+c]*t1s[c];
        vb[o] = a;
    }
    for (int i = tid; i < 16384; i += 256) {
        int c = i >> 8, o = i & 255;
        f1w[i] = fc1_w[o*64+c] * s2s[c];
    }
    if (tid < 256) {
        float a = fc1_b[tid];
        for (int c = 0; c < 64; c++) a += fc1_w[tid*64+c]*t2s[c];
        f1b[tid] = a;
    }
    for (int i = tid; i < 16384; i += 256) {
        int c = i >> 6, o = i & 63;
        f2w[i] = fc2_w[o*256+c] * s3s[c];
    }
    if (tid < 64) {
        float a = fc2_b[tid];
        for (int c = 0; c < 256; c++) a += fc2_w[tid*256+c]*t3s[c];
        f2b[tid] = a;
    }
}

// Fused: gate(x) -> qkv -> window attention -> hp + shortcut -> s1
// one block per 8x8 window
__global__ __launch_bounds__(256) void k2_attn(
    const float* __restrict__ x,
    const float* __restrict__ pa_w, const float* __restrict__ pa_b,
    const float* __restrict__ hp_w, const float* __restrict__ hp_b,
    const float* __restrict__ wsw, float* __restrict__ s1out)
{
    __shared__ float xs[6400];   // [64][100] halo; reused as att[64][64]
    __shared__ float gl[4096];   // gated x, [c][n]
    int tid = threadIdx.x;
    int wid = blockIdx.x;
    int b = wid >> 12;
    int r = wid & 4095;
    int wy = r >> 6, wx = r & 63;
    int y0 = wy*8 - 1, x0 = wx*8 - 1;
    const float* xb = x + (size_t)b * CH * HW;

    for (int i = tid; i < 6400; i += 256) {
        int c = i / 100, p = i - c*100;
        int py = p / 10, px = p - py*10;
        int yy = y0 + py, xx = x0 + px;
        float v = 0.f;
        if (yy >= 0 && yy < HH && xx >= 0 && xx < WW)
            v = xb[(size_t)c*HW + yy*WW + xx];
        xs[i] = v;
    }
    __syncthreads();

    // depthwise 3x3 + sigmoid gate (window pixels only)
    for (int i = tid; i < 4096; i += 256) {
        int c = i >> 6, n = i & 63;
        int yy = n >> 3, xx = n & 7;
        const float* xc = xs + c*100;
        float conv = pa_b[c];
        #pragma unroll
        for (int dy = 0; dy < 3; dy++)
            #pragma unroll
            for (int dx = 0; dx < 3; dx++)
                conv += xc[(yy+dy)*10 + xx+dx] * pa_w[c*9 + dy*3 + dx];
        float xv = xc[(yy+1)*10 + xx+1];
        gl[i] = xv / (1.f + expf(-conv));
    }
    __syncthreads();

    const float* qw = wsw;
    const float* qb = qw + 2048;
    const float* kw = qb + 32;
    const float* kb = kw + 2048;
    const float* vw = kb + 32;
    const float* vb = vw + 4096;

    int hd = tid >> 4, l = tid & 15;    // 16 heads x 16 lanes; 4 pixels per lane
    float q0[4], q1[4], k0[4], k1[4], vv[4][4];
    {
        float bq0 = qb[hd*2], bq1 = qb[hd*2+1], bk0 = kb[hd*2], bk1 = kb[hd*2+1];
        float bv0 = vb[hd*4], bv1 = vb[hd*4+1], bv2 = vb[hd*4+2], bv3 = vb[hd*4+3];
        #pragma unroll
        for (int j = 0; j < 4; j++) {
            q0[j]=bq0; q1[j]=bq1; k0[j]=bk0; k1[j]=bk1;
            vv[j][0]=bv0; vv[j][1]=bv1; vv[j][2]=bv2; vv[j][3]=bv3;
        }
    }
    for (int c = 0; c < 64; c++) {
        float wq0 = qw[(hd*2)*64+c],   wq1 = qw[(hd*2+1)*64+c];
        float wk0 = kw[(hd*2)*64+c],   wk1 = kw[(hd*2+1)*64+c];
        float wv0 = vw[(hd*4)*64+c],   wv1 = vw[(hd*4+1)*64+c];
        float wv2 = vw[(hd*4+2)*64+c], wv3 = vw[(hd*4+3)*64+c];
        #pragma unroll
        for (int j = 0; j < 4; j++) {
            float g = gl[c*64 + l + 16*j];
            q0[j] += wq0*g; q1[j] += wq1*g;
            k0[j] += wk0*g; k1[j] += wk1*g;
            vv[j][0] += wv0*g; vv[j][1] += wv1*g;
            vv[j][2] += wv2*g; vv[j][3] += wv3*g;
        }
    }
    // q softmax over d (2 elements)
    #pragma unroll
    for (int j = 0; j < 4; j++) {
        float m = fmaxf(q0[j], q1[j]);
        float e0 = expf(q0[j]-m), e1 = expf(q1[j]-m);
        float inv = 1.f/(e0+e1);
        q0[j] = e0*inv; q1[j] = e1*inv;
    }
    // k softmax over n (64, spread over 16 lanes x 4)
    float m0 = fmaxf(fmaxf(k0[0],k0[1]), fmaxf(k0[2],k0[3]));
    float m1 = fmaxf(fmaxf(k1[0],k1[1]), fmaxf(k1[2],k1[3]));
    #pragma unroll
    for (int s = 1; s < 16; s <<= 1) {
        m0 = fmaxf(m0, __shfl_xor(m0, s, 64));
        m1 = fmaxf(m1, __shfl_xor(m1, s, 64));
    }
    float sum0 = 0.f, sum1 = 0.f;
    #pragma unroll
    for (int j = 0; j < 4; j++) {
        k0[j] = expf(k0[j]-m0); k1[j] = expf(k1[j]-m1);
        sum0 += k0[j]; sum1 += k1[j];
    }
    #pragma unroll
    for (int s = 1; s < 16; s <<= 1) {
        sum0 += __shfl_xor(sum0, s, 64);
        sum1 += __shfl_xor(sum1, s, 64);
    }
    float iv0 = 1.f/sum0, iv1 = 1.f/sum1;
    #pragma unroll
    for (int j = 0; j < 4; j++) { k0[j] *= iv0; k1[j] *= iv1; }
    // ctx[2][4] = k^T v
    float ctx[2][4];
    #pragma unroll
    for (int e = 0; e < 4; e++) {
        float c0 = 0.f, c1 = 0.f;
        #pragma unroll
        for (int j = 0; j < 4; j++) { c0 += k0[j]*vv[j][e]; c1 += k1[j]*vv[j][e]; }
        #pragma unroll
        for (int s = 1; s < 16; s <<= 1) {
            c0 += __shfl_xor(c0, s, 64);
            c1 += __shfl_xor(c1, s, 64);
        }
        ctx[0][e] = c0; ctx[1][e] = c1;
    }
    // dots = q^T k * scale; dc = max + mean
    float p00=0.f, p01=0.f, p10=0.f, p11=0.f;
    #pragma unroll
    for (int j = 0; j < 4; j++) {
        p00 += q0[j]*k0[j]; p01 += q0[j]*k1[j];
        p10 += q1[j]*k0[j]; p11 += q1[j]*k1[j];
    }
    #pragma unroll
    for (int s = 1; s < 16; s <<= 1) {
        p00 += __shfl_xor(p00, s, 64); p01 += __shfl_xor(p01, s, 64);
        p10 += __shfl_xor(p10, s, 64); p11 += __shfl_xor(p11, s, 64);
    }
    const float CH_SCALE = 0.70710678118654752f;
    p00 *= CH_SCALE; p01 *= CH_SCALE; p10 *= CH_SCALE; p11 *= CH_SCALE;
    float dc = fmaxf(fmaxf(p00,p01), fmaxf(p10,p11)) + 0.25f*(p00+p01+p10+p11);

    float* att = xs;   // reuse halo LDS (all reads of xs finished before gate barrier)
    #pragma unroll
    for (int j = 0; j < 4; j++) {
        int n = l + 16*j;
        #pragma unroll
        for (int e = 0; e < 4; e++) {
            float a = (q0[j]*ctx[0][e] + q1[j]*ctx[1][e]) * dc;
            att[(hd*4+e)*64 + n] = a;
        }
    }
    __syncthreads();

    // hp 1x1 + shortcut
    int p = tid & 63, co = tid >> 6;
    float acc[16];
    #pragma unroll
    for (int i = 0; i < 16; i++) acc[i] = hp_b[co*16+i];
    for (int c = 0; c < 64; c++) {
        float av = att[c*64 + p];
        #pragma unroll
        for (int i = 0; i < 16; i++) acc[i] += hp_w[(co*16+i)*64 + c] * av;
    }
    int yy = wy*8 + (p >> 3), xx = wx*8 + (p & 7);
    size_t base = (size_t)b * CH * HW + (size_t)yy * WW + xx;
    #pragma unroll
    for (int i = 0; i < 16; i++) {
        int o = co*16 + i;
        s1out[base + (size_t)o * HW] = acc[i] + gl[o*64 + p];
    }
}

// fc1 (bn2 folded) + exact GELU -> h (bf16, NHWC)
// block: 64-pixel tile x 128-out half (blockIdx.y)
__global__ __launch_bounds__(256) void k3_fc1(
    const float* __restrict__ s1, const float* __restrict__ wsw,
    uint16_t* __restrict__ h)
{
    __shared__ float wl[64*128];  // [c][128]
    __shared__ float sl[64*64];   // [c][64 px]
    const float* f1w = wsw + 8320;
    const float* f1b = f1w + 16384;
    int tid = threadIdx.x;
    int ho = blockIdx.y;

    for (int i = tid; i < 8192; i += 256) {
        int c = i >> 7, o = i & 127;
        wl[i] = f1w[c*256 + ho*128 + o];
    }
    size_t P = (size_t)blockIdx.x * 64;
    int bb = (int)(P / HW);
    int rr = (int)(P - (size_t)bb * HW);
    const float* sb = s1 + (size_t)bb * CH * HW + rr;
    for (int i = tid; i < 4096; i += 256) {
        int c = i >> 6, j = i & 63;
        sl[i] = sb[(size_t)c * HW + j];
    }
    __syncthreads();

    int pc = tid & 15, oc = tid >> 4;   // 4 pixels, 8 outs
    float acc[4][8];
    #pragma unroll
    for (int k = 0; k < 4; k++)
        #pragma unroll
        for (int i = 0; i < 8; i++) acc[k][i] = f1b[ho*128 + oc*8 + i];
    for (int c = 0; c < 64; c++) {
        float4 s4 = *reinterpret_cast<const float4*>(&sl[c*64 + pc*4]);
        float4 w0 = *reinterpret_cast<const float4*>(&wl[c*128 + oc*8]);
        float4 w1 = *reinterpret_cast<const float4*>(&wl[c*128 + oc*8 + 4]);
        float xv[4] = {s4.x, s4.y, s4.z, s4.w};
        float wv[8] = {w0.x, w0.y, w0.z, w0.w, w1.x, w1.y, w1.z, w1.w};
        #pragma unroll
        for (int k = 0; k < 4; k++)
            #pragma unroll
            for (int i = 0; i < 8; i++) acc[k][i] += xv[k]*wv[i];
    }
    #pragma unroll
    for (int k = 0; k < 4; k++) {
        uint16_t tmp[8];
        #pragma unroll
        for (int i = 0; i < 8; i++) {
            float v = acc[k][i];
            float gv = 0.5f * v * (1.f + erff(v * 0.70710678118654752f));
            tmp[i] = f2bf(gv);
        }
        size_t p = P + pc*4 + k;
        *reinterpret_cast<uint4*>(&h[p*256 + ho*128 + oc*8]) =
            *reinterpret_cast<const uint4*>(tmp);
    }
}

// dwconv3(h) (+bn3 folded) -> fc2 -> + s1 -> out ; 16x16 pixel tile, 64-ch chunks
__global__ __launch_bounds__(256) void k4_mlp2(
    const uint16_t* __restrict__ h, const float* __restrict__ dw_w,
    const float* __restrict__ wsw, const float* __restrict__ s1,
    float* __restrict__ out)
{
    __shared__ uint16_t hl[324*66];  // 18x18 halo x 64 ch (padded stride 66)
    __shared__ float wl[64*64];      // fc2 chunk [c][64]
    const float* f2w = wsw + 24960;
    const float* f2b = wsw + 41344;
    int tid = threadIdx.x;
    int X = blockIdx.x * 16, Y = blockIdx.y * 16;
    int b = blockIdx.z;
    int tx = tid & 15, ty = tid >> 4;

    float acc[64];
    #pragma unroll
    for (int o = 0; o < 64; o++) acc[o] = f2b[o];

    const uint16_t* hb = h + (size_t)b * HW * 256;
    for (int cc = 0; cc < 4; cc++) {
        __syncthreads();
        for (int i = tid; i < 2592; i += 256) {   // 324 px * 8 groups of 8ch
            int px = i >> 3, sub = i & 7;
            int hy = px / 18, hx = px - hy*18;
            int yy = Y - 1 + hy, xx = X - 1 + hx;
            uint4 q = {0u, 0u, 0u, 0u};
            if (yy >= 0 && yy < HH && xx >= 0 && xx < WW)
                q = *reinterpret_cast<const uint4*>(
                    &hb[((size_t)yy*WW + xx)*256 + cc*64 + sub*8]);
            uint32_t* d = reinterpret_cast<uint32_t*>(&hl[px*66 + sub*8]);
            d[0] = q.x; d[1] = q.y; d[2] = q.z; d[3] = q.w;
        }
        for (int i = tid; i < 4096; i += 256) wl[i] = f2w[cc*4096 + i];
        __syncthreads();

        for (int c2 = 0; c2 < 32; c2++) {
            int c = c2 * 2;
            float t0 = 0.f, t1 = 0.f;
            #pragma unroll
            for (int dy = 0; dy < 3; dy++) {
                #pragma unroll
                for (int dx = 0; dx < 3; dx++) {
                    uint32_t u = *reinterpret_cast<const uint32_t*>(
                        &hl[((ty+dy)*18 + tx+dx)*66 + c]);
                    float w0 = dw_w[(cc*64+c)*9 + dy*3 + dx];
                    float w1 = dw_w[(cc*64+c+1)*9 + dy*3 + dx];
                    t0 += bf2f((uint16_t)(u & 0xffffu)) * w0;
                    t1 += bf2f((uint16_t)(u >> 16)) * w1;
                }
            }
            const float4* w4a = reinterpret_cast<const float4*>(&wl[c*64]);
            const float4* w4b = reinterpret_cast<const float4*>(&wl[(c+1)*64]);
            #pragma unroll
            for (int o4 = 0; o4 < 16; o4++) {
                float4 a = w4a[o4], bb = w4b[o4];
                acc[o4*4+0] += a.x*t0 + bb.x*t1;
                acc[o4*4+1] += a.y*t0 + bb.y*t1;
                acc[o4*4+2] += a.z*t0 + bb.z*t1;
                acc[o4*4+3] += a.w*t0 + bb.w*t1;
            }
        }
    }
    size_t base = (size_t)b * CH * HW + (size_t)(Y+ty) * WW + (X+tx);
    #pragma unroll
    for (int o = 0; o < 64; o++) {
        size_t idx = base + (size_t)o * HW;
        out[idx] = acc[o] + s1[idx];
    }
}

extern "C" void kernel_launch(void* const* d_in, const int* in_sizes, int n_in,
                              void* d_out, int out_size, void* d_ws, size_t ws_size,
                              hipStream_t stream) {
    const float* x     = (const float*)d_in[0];
    const float* pa_w  = (const float*)d_in[1];
    const float* pa_b  = (const float*)d_in[2];
    const float* bn1_g = (const float*)d_in[3];
    const float* bn1_b = (const float*)d_in[4];
    const float* bn1_m = (const float*)d_in[5];
    const float* bn1_v = (const float*)d_in[6];
    const float* q_w   = (const float*)d_in[7];
    const float* q_b   = (const float*)d_in[8];
    const float* k_w   = (const float*)d_in[9];
    const float* k_b   = (const float*)d_in[10];
    const float* v_w   = (const float*)d_in[11];
    const float* v_b   = (const float*)d_in[12];
    const float* hp_w  = (const float*)d_in[13];
    const float* hp_b  = (const float*)d_in[14];
    const float* bn2_g = (const float*)d_in[15];
    const float* bn2_b = (const float*)d_in[16];
    const float* bn2_m = (const float*)d_in[17];
    const float* bn2_v = (const float*)d_in[18];
    const float* fc1_w = (const float*)d_in[19];
    const float* fc1_b = (const float*)d_in[20];
    const float* dw_w  = (const float*)d_in[21];
    const float* dw_b  = (const float*)d_in[22];
    const float* bn3_g = (const float*)d_in[23];
    const float* bn3_b = (const float*)d_in[24];
    const float* bn3_m = (const float*)d_in[25];
    const float* bn3_v = (const float*)d_in[26];
    const float* fc2_w = (const float*)d_in[27];
    const float* fc2_b = (const float*)d_in[28];

    float*    s1  = (float*)d_ws;                                   // 134,217,728 B
    uint16_t* h   = (uint16_t*)((char*)d_ws + 134217728);           // 268,435,456 B
    float*    wsw = (float*)((char*)d_ws + 134217728 + 268435456);  // 165,632 B

    k0_fold<<<dim3(1), dim3(256), 0, stream>>>(
        q_w, q_b, k_w, k_b, v_w, v_b,
        bn1_g, bn1_b, bn1_m, bn1_v,
        fc1_w, fc1_b, bn2_g, bn2_b, bn2_m, bn2_v,
        fc2_w, fc2_b, dw_b, bn3_g, bn3_b, bn3_m, bn3_v, wsw);

    k2_attn<<<dim3(8192), dim3(256), 0, stream>>>(
        x, pa_w, pa_b, hp_w, hp_b, wsw, s1);

    k3_fc1<<<dim3(8192, 2), dim3(256), 0, stream>>>(s1, wsw, h);

    k4_mlp2<<<dim3(32, 32, 2), dim3(256), 0, stream>>>(
        h, dw_w, wsw, s1, (float*)d_out);
}

// Round 2
// 1672.550 us; speedup vs baseline: 1.0659x; 1.0659x over previous
//
#include <hip/hip_runtime.h>
#include <stdint.h>

#define HH 512
#define WW 512
#define HW 262144
#define CH 64
#define HID 256

__device__ __forceinline__ float bf2f(uint16_t u) {
    return __uint_as_float(((uint32_t)u) << 16);
}
__device__ __forceinline__ uint16_t f2bf(float f) {
    uint32_t x = __float_as_uint(f);
    uint32_t r = x + 0x7fffu + ((x >> 16) & 1u);
    return (uint16_t)(r >> 16);
}

// ws float layout (after s1 + h byte regions):
// qw 2048 | qb 32 | kw 2048 | kb 32 | vw 4096 | vb 64   (=8320)
// f1w [c][256] 16384 | f1b 256                           (=24960)
// f2w [c][64] 16384  | f2b 64                            (=41408 floats)

__global__ __launch_bounds__(256) void k0_fold(
    const float* __restrict__ q_w, const float* __restrict__ q_b,
    const float* __restrict__ k_w, const float* __restrict__ k_b,
    const float* __restrict__ v_w, const float* __restrict__ v_b,
    const float* __restrict__ bn1_g, const float* __restrict__ bn1_b,
    const float* __restrict__ bn1_m, const float* __restrict__ bn1_v,
    const float* __restrict__ fc1_w, const float* __restrict__ fc1_b,
    const float* __restrict__ bn2_g, const float* __restrict__ bn2_b,
    const float* __restrict__ bn2_m, const float* __restrict__ bn2_v,
    const float* __restrict__ fc2_w, const float* __restrict__ fc2_b,
    const float* __restrict__ dw_b,
    const float* __restrict__ bn3_g, const float* __restrict__ bn3_b,
    const float* __restrict__ bn3_m, const float* __restrict__ bn3_v,
    float* __restrict__ wsw)
{
    __shared__ float s1s[64], t1s[64], s2s[64], t2s[64], s3s[256], t3s[256];
    int tid = threadIdx.x;
    if (tid < 64) {
        float s = bn1_g[tid] * rsqrtf(bn1_v[tid] + 1e-5f);
        s1s[tid] = s; t1s[tid] = bn1_b[tid] - bn1_m[tid] * s;
        float s2 = bn2_g[tid] * rsqrtf(bn2_v[tid] + 1e-5f);
        s2s[tid] = s2; t2s[tid] = bn2_b[tid] - bn2_m[tid] * s2;
    }
    if (tid < 256) {
        float s = bn3_g[tid] * rsqrtf(bn3_v[tid] + 1e-5f);
        s3s[tid] = s;
        t3s[tid] = (dw_b[tid] - bn3_m[tid]) * s + bn3_b[tid];
    }
    __syncthreads();
    float* qw = wsw;
    float* qb = qw + 2048;
    float* kw = qb + 32;
    float* kb = kw + 2048;
    float* vw = kb + 32;
    float* vb = vw + 4096;
    float* f1w = vb + 64;
    float* f1b = f1w + 16384;
    float* f2w = f1b + 256;
    float* f2b = f2w + 16384;

    for (int i = tid; i < 2048; i += 256) {
        int c = i & 63;
        qw[i] = q_w[i] * s1s[c];
        kw[i] = k_w[i] * s1s[c];
    }
    for (int i = tid; i < 4096; i += 256) {
        int c = i & 63;
        vw[i] = v_w[i] * s1s[c];
    }
    if (tid < 32) {
        float a = q_b[tid], b = k_b[tid];
        for (int c = 0; c < 64; c++) { a += q_w[tid*64+c]*t1s[c]; b += k_w[tid*64+c]*t1s[c]; }
        qb[tid] = a; kb[tid] = b;
    }
    if (tid >= 64 && tid < 128) {
        int o = tid - 64;
        float a = v_b[o];
        for (int c = 0; c < 64; c++) a += v_w[o*64+c]*t1s[c];
        vb[o] = a;
    }
    for (int i = tid; i < 16384; i += 256) {
        int c = i >> 8, o = i & 255;
        f1w[i] = fc1_w[o*64+c] * s2s[c];
    }
    if (tid < 256) {
        float a = fc1_b[tid];
        for (int c = 0; c < 64; c++) a += fc1_w[tid*64+c]*t2s[c];
        f1b[tid] = a;
    }
    for (int i = tid; i < 16384; i += 256) {
        int c = i >> 6, o = i & 63;
        f2w[i] = fc2_w[o*256+c] * s3s[c];
    }
    if (tid < 64) {
        float a = fc2_b[tid];
        for (int c = 0; c < 256; c++) a += fc2_w[tid*256+c]*t3s[c];
        f2b[tid] = a;
    }
}

// Fused: gate(x) -> qkv -> window attention -> hp + shortcut -> s1
// one block per 8x8 window. LDS 34.8KB -> 4 blocks/CU.
__global__ __launch_bounds__(256, 4) void k2_attn(
    const float* __restrict__ x,
    const float* __restrict__ pa_w, const float* __restrict__ pa_b,
    const float* __restrict__ hp_w, const float* __restrict__ hp_b,
    const float* __restrict__ wsw, float* __restrict__ s1out)
{
    // regionA: phase 1 = bf16 halo [64][102] (13056B) + pa_w (576f) + pa_b (64f)
    //          phase 2 = att [64 attch][68 px-stride] fp32 (17408B)
    __shared__ __align__(16) float regionA[4352];
    __shared__ __align__(16) float gl[4352];   // gated x, [n px][68 ch-stride]
    uint16_t* xs = (uint16_t*)regionA;
    float* paw = regionA + 3264;
    float* pab = regionA + 3840;
    float* att = regionA;

    int tid = threadIdx.x;
    int wid = blockIdx.x;
    int b = wid >> 12;
    int r = wid & 4095;
    int wy = r >> 6, wx = r & 63;
    int y0 = wy*8 - 1, x0 = wx*8 - 1;
    const float* xb = x + (size_t)b * CH * HW;

    for (int i = tid; i < 6400; i += 256) {
        int c = i / 100, p = i - c*100;
        int py = p / 10, px = p - py*10;
        int yy = y0 + py, xx = x0 + px;
        float v = 0.f;
        if (yy >= 0 && yy < HH && xx >= 0 && xx < WW)
            v = xb[(size_t)c*HW + yy*WW + xx];
        xs[c*102 + p] = f2bf(v);
    }
    for (int i = tid; i < 576; i += 256) paw[i] = pa_w[i];
    if (tid < 64) pab[tid] = pa_b[tid];
    __syncthreads();

    // depthwise 3x3 + sigmoid gate; write gl transposed [n][c], pad 68
    for (int i = tid; i < 4096; i += 256) {
        int c = i & 63, n = i >> 6;
        int yy = n >> 3, xx = n & 7;
        const uint16_t* xc = xs + c*102;
        float conv = pab[c];
        #pragma unroll
        for (int dy = 0; dy < 3; dy++)
            #pragma unroll
            for (int dx = 0; dx < 3; dx++)
                conv += bf2f(xc[(yy+dy)*10 + xx+dx]) * paw[c*9 + dy*3 + dx];
        float xv = bf2f(xc[(yy+1)*10 + xx+1]);
        gl[n*68 + c] = xv / (1.f + expf(-conv));
    }
    __syncthreads();

    const float* qw = wsw;
    const float* qb = qw + 2048;
    const float* kw = qb + 32;
    const float* kb = kw + 2048;
    const float* vw = kb + 32;
    const float* vb = vw + 4096;

    int hd = tid >> 4, l = tid & 15;    // 16 heads x 16 lanes; 4 pixels/lane
    const float* wr0 = qw + (hd*2  )*64;
    const float* wr1 = qw + (hd*2+1)*64;
    const float* wr2 = kw + (hd*2  )*64;
    const float* wr3 = kw + (hd*2+1)*64;
    const float* wr4 = vw + (hd*4  )*64;
    const float* wr5 = vw + (hd*4+1)*64;
    const float* wr6 = vw + (hd*4+2)*64;
    const float* wr7 = vw + (hd*4+3)*64;

    float a0[4], a1[4], a2[4], a3[4], a4[4], a5[4], a6[4], a7[4];
    {
        float b0 = qb[hd*2], b1 = qb[hd*2+1], b2 = kb[hd*2], b3 = kb[hd*2+1];
        float b4 = vb[hd*4], b5 = vb[hd*4+1], b6 = vb[hd*4+2], b7 = vb[hd*4+3];
        #pragma unroll
        for (int j = 0; j < 4; j++) {
            a0[j]=b0; a1[j]=b1; a2[j]=b2; a3[j]=b3;
            a4[j]=b4; a5[j]=b5; a6[j]=b6; a7[j]=b7;
        }
    }
    for (int cc = 0; cc < 16; cc++) {
        float4 g0 = *(const float4*)&gl[(l    )*68 + cc*4];
        float4 g1 = *(const float4*)&gl[(l+16)*68 + cc*4];
        float4 g2 = *(const float4*)&gl[(l+32)*68 + cc*4];
        float4 g3 = *(const float4*)&gl[(l+48)*68 + cc*4];
        float4 w;
#define PROJ_ROW(AR, WP) \
        w = *(const float4*)&WP[cc*4]; \
        AR[0] += w.x*g0.x + w.y*g0.y + w.z*g0.z + w.w*g0.w; \
        AR[1] += w.x*g1.x + w.y*g1.y + w.z*g1.z + w.w*g1.w; \
        AR[2] += w.x*g2.x + w.y*g2.y + w.z*g2.z + w.w*g2.w; \
        AR[3] += w.x*g3.x + w.y*g3.y + w.z*g3.z + w.w*g3.w;
        PROJ_ROW(a0, wr0) PROJ_ROW(a1, wr1) PROJ_ROW(a2, wr2) PROJ_ROW(a3, wr3)
        PROJ_ROW(a4, wr4) PROJ_ROW(a5, wr5) PROJ_ROW(a6, wr6) PROJ_ROW(a7, wr7)
#undef PROJ_ROW
    }

    // q softmax over d (2 elements)
    #pragma unroll
    for (int j = 0; j < 4; j++) {
        float m = fmaxf(a0[j], a1[j]);
        float e0 = expf(a0[j]-m), e1 = expf(a1[j]-m);
        float inv = 1.f/(e0+e1);
        a0[j] = e0*inv; a1[j] = e1*inv;
    }
    // k softmax over n (64, spread over 16 lanes x 4)
    float m0 = fmaxf(fmaxf(a2[0],a2[1]), fmaxf(a2[2],a2[3]));
    float m1 = fmaxf(fmaxf(a3[0],a3[1]), fmaxf(a3[2],a3[3]));
    #pragma unroll
    for (int s = 1; s < 16; s <<= 1) {
        m0 = fmaxf(m0, __shfl_xor(m0, s, 64));
        m1 = fmaxf(m1, __shfl_xor(m1, s, 64));
    }
    float sum0 = 0.f, sum1 = 0.f;
    #pragma unroll
    for (int j = 0; j < 4; j++) {
        a2[j] = expf(a2[j]-m0); a3[j] = expf(a3[j]-m1);
        sum0 += a2[j]; sum1 += a3[j];
    }
    #pragma unroll
    for (int s = 1; s < 16; s <<= 1) {
        sum0 += __shfl_xor(sum0, s, 64);
        sum1 += __shfl_xor(sum1, s, 64);
    }
    float iv0 = 1.f/sum0, iv1 = 1.f/sum1;
    #pragma unroll
    for (int j = 0; j < 4; j++) { a2[j] *= iv0; a3[j] *= iv1; }
    // ctx[2][4] = k^T v
    float ctx0[4], ctx1[4];
    #pragma unroll
    for (int e = 0; e < 4; e++) {
        float ve0, ve1, ve2, ve3;
        if (e==0) { ve0=a4[0]; ve1=a4[1]; ve2=a4[2]; ve3=a4[3]; }
        else if (e==1) { ve0=a5[0]; ve1=a5[1]; ve2=a5[2]; ve3=a5[3]; }
        else if (e==2) { ve0=a6[0]; ve1=a6[1]; ve2=a6[2]; ve3=a6[3]; }
        else { ve0=a7[0]; ve1=a7[1]; ve2=a7[2]; ve3=a7[3]; }
        float c0 = a2[0]*ve0 + a2[1]*ve1 + a2[2]*ve2 + a2[3]*ve3;
        float c1 = a3[0]*ve0 + a3[1]*ve1 + a3[2]*ve2 + a3[3]*ve3;
        #pragma unroll
        for (int s = 1; s < 16; s <<= 1) {
            c0 += __shfl_xor(c0, s, 64);
            c1 += __shfl_xor(c1, s, 64);
        }
        ctx0[e] = c0; ctx1[e] = c1;
    }
    // dots = q^T k * scale; dc = max + mean
    float p00=0.f, p01=0.f, p10=0.f, p11=0.f;
    #pragma unroll
    for (int j = 0; j < 4; j++) {
        p00 += a0[j]*a2[j]; p01 += a0[j]*a3[j];
        p10 += a1[j]*a2[j]; p11 += a1[j]*a3[j];
    }
    #pragma unroll
    for (int s = 1; s < 16; s <<= 1) {
        p00 += __shfl_xor(p00, s, 64); p01 += __shfl_xor(p01, s, 64);
        p10 += __shfl_xor(p10, s, 64); p11 += __shfl_xor(p11, s, 64);
    }
    const float CH_SCALE = 0.70710678118654752f;
    p00 *= CH_SCALE; p01 *= CH_SCALE; p10 *= CH_SCALE; p11 *= CH_SCALE;
    float dc = fmaxf(fmaxf(p00,p01), fmaxf(p10,p11)) + 0.25f*(p00+p01+p10+p11);

    // att [attch][68 px-stride] in regionA (halo reads all complete)
    #pragma unroll
    for (int j = 0; j < 4; j++) {
        int n = l + 16*j;
        att[(hd*4+0)*68 + n] = (a0[j]*ctx0[0] + a1[j]*ctx1[0]) * dc;
        att[(hd*4+1)*68 + n] = (a0[j]*ctx0[1] + a1[j]*ctx1[1]) * dc;
        att[(hd*4+2)*68 + n] = (a0[j]*ctx0[2] + a1[j]*ctx1[2]) * dc;
        att[(hd*4+3)*68 + n] = (a0[j]*ctx0[3] + a1[j]*ctx1[3]) * dc;
    }
    __syncthreads();

    // hp 1x1 + shortcut
    int p = tid & 63, co = tid >> 6;
    float oa[16];
    #pragma unroll
    for (int i = 0; i < 16; i++) oa[i] = hp_b[co*16+i];
    for (int cc = 0; cc < 16; cc++) {
        float av0 = att[(cc*4+0)*68 + p];
        float av1 = att[(cc*4+1)*68 + p];
        float av2 = att[(cc*4+2)*68 + p];
        float av3 = att[(cc*4+3)*68 + p];
        #pragma unroll
        for (int i = 0; i < 16; i++) {
            float4 w = *(const float4*)&hp_w[(co*16+i)*64 + cc*4];
            oa[i] += w.x*av0 + w.y*av1 + w.z*av2 + w.w*av3;
        }
    }
    int yy = wy*8 + (p >> 3), xx = wx*8 + (p & 7);
    size_t base = (size_t)b * CH * HW + (size_t)yy * WW + xx;
    #pragma unroll
    for (int i4 = 0; i4 < 4; i4++) {
        float4 g = *(const float4*)&gl[p*68 + co*16 + i4*4];
        s1out[base + (size_t)(co*16+i4*4+0)*HW] = oa[i4*4+0] + g.x;
        s1out[base + (size_t)(co*16+i4*4+1)*HW] = oa[i4*4+1] + g.y;
        s1out[base + (size_t)(co*16+i4*4+2)*HW] = oa[i4*4+2] + g.z;
        s1out[base + (size_t)(co*16+i4*4+3)*HW] = oa[i4*4+3] + g.w;
    }
}

// fc1 (bn2 folded) + exact GELU -> h (bf16, NHWC)
__global__ __launch_bounds__(256) void k3_fc1(
    const float* __restrict__ s1, const float* __restrict__ wsw,
    uint16_t* __restrict__ h)
{
    __shared__ float wl[64*128];  // [c][128]
    __shared__ float sl[64*64];   // [c][64 px]
    const float* f1w = wsw + 8320;
    const float* f1b = f1w + 16384;
    int tid = threadIdx.x;
    int ho = blockIdx.y;

    for (int i = tid; i < 8192; i += 256) {
        int c = i >> 7, o = i & 127;
        wl[i] = f1w[c*256 + ho*128 + o];
    }
    size_t P = (size_t)blockIdx.x * 64;
    int bb = (int)(P / HW);
    int rr = (int)(P - (size_t)bb * HW);
    const float* sb = s1 + (size_t)bb * CH * HW + rr;
    for (int i = tid; i < 4096; i += 256) {
        int c = i >> 6, j = i & 63;
        sl[i] = sb[(size_t)c * HW + j];
    }
    __syncthreads();

    int pc = tid & 15, oc = tid >> 4;   // 4 pixels, 8 outs
    float acc[4][8];
    #pragma unroll
    for (int k = 0; k < 4; k++)
        #pragma unroll
        for (int i = 0; i < 8; i++) acc[k][i] = f1b[ho*128 + oc*8 + i];
    for (int c = 0; c < 64; c++) {
        float4 s4 = *reinterpret_cast<const float4*>(&sl[c*64 + pc*4]);
        float4 w0 = *reinterpret_cast<const float4*>(&wl[c*128 + oc*8]);
        float4 w1 = *reinterpret_cast<const float4*>(&wl[c*128 + oc*8 + 4]);
        float xv[4] = {s4.x, s4.y, s4.z, s4.w};
        float wv[8] = {w0.x, w0.y, w0.z, w0.w, w1.x, w1.y, w1.z, w1.w};
        #pragma unroll
        for (int k = 0; k < 4; k++)
            #pragma unroll
            for (int i = 0; i < 8; i++) acc[k][i] += xv[k]*wv[i];
    }
    #pragma unroll
    for (int k = 0; k < 4; k++) {
        uint16_t tmp[8];
        #pragma unroll
        for (int i = 0; i < 8; i++) {
            float v = acc[k][i];
            float gv = 0.5f * v * (1.f + erff(v * 0.70710678118654752f));
            tmp[i] = f2bf(gv);
        }
        size_t p = P + pc*4 + k;
        *reinterpret_cast<uint4*>(&h[p*256 + ho*128 + oc*8]) =
            *reinterpret_cast<const uint4*>(tmp);
    }
}

// dwconv3(h) (+bn3 folded) -> fc2 -> + s1 -> out ; 16x16 tile, 64-ch chunks.
// fc2/dw weights read via wave-uniform global addresses -> scalar loads.
__global__ __launch_bounds__(256, 3) void k4_mlp2(
    const uint16_t* __restrict__ h, const float* __restrict__ dw_w,
    const float* __restrict__ wsw, const float* __restrict__ s1,
    float* __restrict__ out)
{
    __shared__ uint16_t hl[324*66];  // 18x18 halo x 64 ch (padded stride 66)
    const float* f2w = wsw + 24960;
    const float* f2b = wsw + 41344;
    int tid = threadIdx.x;
    int X = blockIdx.x * 16, Y = blockIdx.y * 16;
    int b = blockIdx.z;
    int tx = tid & 15, ty = tid >> 4;

    float acc[64];
    #pragma unroll
    for (int o = 0; o < 64; o++) acc[o] = f2b[o];

    const uint16_t* hb = h + (size_t)b * HW * 256;
    for (int cc = 0; cc < 4; cc++) {
        __syncthreads();
        for (int i = tid; i < 2592; i += 256) {   // 324 px * 8 groups of 8ch
            int px = i >> 3, sub = i & 7;
            int hy = px / 18, hx = px - hy*18;
            int yy = Y - 1 + hy, xx = X - 1 + hx;
            uint4 q = {0u, 0u, 0u, 0u};
            if (yy >= 0 && yy < HH && xx >= 0 && xx < WW)
                q = *reinterpret_cast<const uint4*>(
                    &hb[((size_t)yy*WW + xx)*256 + cc*64 + sub*8]);
            uint32_t* d = reinterpret_cast<uint32_t*>(&hl[px*66 + sub*8]);
            d[0] = q.x; d[1] = q.y; d[2] = q.z; d[3] = q.w;
        }
        __syncthreads();

        const float* dwc = dw_w + cc*64*9;
        const float* wc  = f2w + cc*4096;
        for (int c2 = 0; c2 < 32; c2++) {
            int c = c2 * 2;
            float t0 = 0.f, t1 = 0.f;
            #pragma unroll
            for (int dy = 0; dy < 3; dy++) {
                #pragma unroll
                for (int dx = 0; dx < 3; dx++) {
                    uint32_t u = *reinterpret_cast<const uint32_t*>(
                        &hl[((ty+dy)*18 + tx+dx)*66 + c]);
                    t0 += bf2f((uint16_t)(u & 0xffffu)) * dwc[c*9 + dy*3 + dx];
                    t1 += bf2f((uint16_t)(u >> 16)) * dwc[(c+1)*9 + dy*3 + dx];
                }
            }
            const float4* w4a = reinterpret_cast<const float4*>(&wc[c*64]);
            const float4* w4b = reinterpret_cast<const float4*>(&wc[(c+1)*64]);
            #pragma unroll
            for (int o4 = 0; o4 < 16; o4++) {
                float4 a = w4a[o4], bb2 = w4b[o4];
                acc[o4*4+0] += a.x*t0 + bb2.x*t1;
                acc[o4*4+1] += a.y*t0 + bb2.y*t1;
                acc[o4*4+2] += a.z*t0 + bb2.z*t1;
                acc[o4*4+3] += a.w*t0 + bb2.w*t1;
            }
        }
    }
    size_t base = (size_t)b * CH * HW + (size_t)(Y+ty) * WW + (X+tx);
    #pragma unroll
    for (int o = 0; o < 64; o++) {
        size_t idx = base + (size_t)o * HW;
        out[idx] = acc[o] + s1[idx];
    }
}

extern "C" void kernel_launch(void* const* d_in, const int* in_sizes, int n_in,
                              void* d_out, int out_size, void* d_ws, size_t ws_size,
                              hipStream_t stream) {
    const float* x     = (const float*)d_in[0];
    const float* pa_w  = (const float*)d_in[1];
    const float* pa_b  = (const float*)d_in[2];
    const float* bn1_g = (const float*)d_in[3];
    const float* bn1_b = (const float*)d_in[4];
    const float* bn1_m = (const float*)d_in[5];
    const float* bn1_v = (const float*)d_in[6];
    const float* q_w   = (const float*)d_in[7];
    const float* q_b   = (const float*)d_in[8];
    const float* k_w   = (const float*)d_in[9];
    const float* k_b   = (const float*)d_in[10];
    const float* v_w   = (const float*)d_in[11];
    const float* v_b   = (const float*)d_in[12];
    const float* hp_w  = (const float*)d_in[13];
    const float* hp_b  = (const float*)d_in[14];
    const float* bn2_g = (const float*)d_in[15];
    const float* bn2_b = (const float*)d_in[16];
    const float* bn2_m = (const float*)d_in[17];
    const float* bn2_v = (const float*)d_in[18];
    const float* fc1_w = (const float*)d_in[19];
    const float* fc1_b = (const float*)d_in[20];
    const float* dw_w  = (const float*)d_in[21];
    const float* dw_b  = (const float*)d_in[22];
    const float* bn3_g = (const float*)d_in[23];
    const float* bn3_b = (const float*)d_in[24];
    const float* bn3_m = (const float*)d_in[25];
    const float* bn3_v = (const float*)d_in[26];
    const float* fc2_w = (const float*)d_in[27];
    const float* fc2_b = (const float*)d_in[28];

    float*    s1  = (float*)d_ws;                                   // 134,217,728 B
    uint16_t* h   = (uint16_t*)((char*)d_ws + 134217728);           // 268,435,456 B
    float*    wsw = (float*)((char*)d_ws + 134217728 + 268435456);  // 165,632 B

    k0_fold<<<dim3(1), dim3(256), 0, stream>>>(
        q_w, q_b, k_w, k_b, v_w, v_b,
        bn1_g, bn1_b, bn1_m, bn1_v,
        fc1_w, fc1_b, bn2_g, bn2_b, bn2_m, bn2_v,
        fc2_w, fc2_b, dw_b, bn3_g, bn3_b, bn3_m, bn3_v, wsw);

    k2_attn<<<dim3(8192), dim3(256), 0, stream>>>(
        x, pa_w, pa_b, hp_w, hp_b, wsw, s1);

    k3_fc1<<<dim3(8192, 2), dim3(256), 0, stream>>>(s1, wsw, h);

    k4_mlp2<<<dim3(32, 32, 2), dim3(256), 0, stream>>>(
        h, dw_w, wsw, s1, (float*)d_out);
}

// Round 3
// 1223.361 us; speedup vs baseline: 1.4572x; 1.3672x over previous
//
#include <hip/hip_runtime.h>
#include <stdint.h>

#define HH 512
#define WW 512
#define HW 262144
#define CH 64
#define HID 256

typedef __attribute__((ext_vector_type(8))) short short8;
typedef __attribute__((ext_vector_type(4))) float f32x4;

__device__ __forceinline__ float bf2f(uint16_t u) {
    return __uint_as_float(((uint32_t)u) << 16);
}
__device__ __forceinline__ uint16_t f2bf(float f) {
    uint32_t x = __float_as_uint(f);
    uint32_t r = x + 0x7fffu + ((x >> 16) & 1u);
    return (uint16_t)(r >> 16);
}

// fast exact-erf GELU (A&S 7.1.26, |err| < 1.5e-7)
__device__ __forceinline__ float gelu_f(float v) {
    float u = v * 0.70710678118654752f;
    float a = fabsf(u);
    float t = 1.f / (1.f + 0.3275911f * a);
    float p = t*(0.254829592f + t*(-0.284496736f + t*(1.421413741f +
              t*(-1.453152027f + t*1.061405429f))));
    float e = __expf(-u*u);
    float er = copysignf(1.f - p*e, u);
    return 0.5f * v * (1.f + er);
}

// ws float layout (after s1 + h byte regions):
// 0: qw 2048 | 2048: qb 32 | 2080: kw 2048 | 4128: kb 32 | 4160: vw 4096
// 8256: vb 64 | 8320: (f1w f32, unused) | 24704: f1b 256 | 24960: (f2w unused)
// 41344: f2b 64 | 41408: dwp 3072 | 44480: w1f (16384 u16) | 52672: w2f (16384 u16)

__global__ __launch_bounds__(256) void k0_fold(
    const float* __restrict__ q_w, const float* __restrict__ q_b,
    const float* __restrict__ k_w, const float* __restrict__ k_b,
    const float* __restrict__ v_w, const float* __restrict__ v_b,
    const float* __restrict__ bn1_g, const float* __restrict__ bn1_b,
    const float* __restrict__ bn1_m, const float* __restrict__ bn1_v,
    const float* __restrict__ fc1_w, const float* __restrict__ fc1_b,
    const float* __restrict__ bn2_g, const float* __restrict__ bn2_b,
    const float* __restrict__ bn2_m, const float* __restrict__ bn2_v,
    const float* __restrict__ fc2_w, const float* __restrict__ fc2_b,
    const float* __restrict__ dw_w, const float* __restrict__ dw_b,
    const float* __restrict__ bn3_g, const float* __restrict__ bn3_b,
    const float* __restrict__ bn3_m, const float* __restrict__ bn3_v,
    float* __restrict__ wsw)
{
    __shared__ float s1s[64], t1s[64], s2s[64], t2s[64], s3s[256], t3s[256];
    int tid = threadIdx.x;
    if (tid < 64) {
        float s = bn1_g[tid] * rsqrtf(bn1_v[tid] + 1e-5f);
        s1s[tid] = s; t1s[tid] = bn1_b[tid] - bn1_m[tid] * s;
        float s2 = bn2_g[tid] * rsqrtf(bn2_v[tid] + 1e-5f);
        s2s[tid] = s2; t2s[tid] = bn2_b[tid] - bn2_m[tid] * s2;
    }
    if (tid < 256) {
        float s = bn3_g[tid] * rsqrtf(bn3_v[tid] + 1e-5f);
        s3s[tid] = s;
        t3s[tid] = (dw_b[tid] - bn3_m[tid]) * s + bn3_b[tid];
    }
    __syncthreads();
    float* qw = wsw;
    float* qb = qw + 2048;
    float* kw = qb + 32;
    float* kb = kw + 2048;
    float* vw = kb + 32;
    float* vb = vw + 4096;
    float* f1b = wsw + 24704;
    float* f2b = wsw + 41344;
    float* dwp = wsw + 41408;
    uint16_t* w1f = (uint16_t*)(wsw + 44480);
    uint16_t* w2f = (uint16_t*)(wsw + 52672);

    for (int i = tid; i < 2048; i += 256) {
        int c = i & 63;
        qw[i] = q_w[i] * s1s[c];
        kw[i] = k_w[i] * s1s[c];
    }
    for (int i = tid; i < 4096; i += 256) {
        int c = i & 63;
        vw[i] = v_w[i] * s1s[c];
    }
    if (tid < 32) {
        float a = q_b[tid], b = k_b[tid];
        for (int c = 0; c < 64; c++) { a += q_w[tid*64+c]*t1s[c]; b += k_w[tid*64+c]*t1s[c]; }
        qb[tid] = a; kb[tid] = b;
    }
    if (tid >= 64 && tid < 128) {
        int o = tid - 64;
        float a = v_b[o];
        for (int c = 0; c < 64; c++) a += v_w[o*64+c]*t1s[c];
        vb[o] = a;
    }
    if (tid < 256) {
        float a = fc1_b[tid];
        for (int c = 0; c < 64; c++) a += fc1_w[tid*64+c]*t2s[c];
        f1b[tid] = a;
    }
    if (tid < 64) {
        float a = fc2_b[tid];
        for (int c = 0; c < 256; c++) a += fc2_w[tid*256+c]*t3s[c];
        f2b[tid] = a;
    }
    // W1 bf16 fragment order: [nt16][k8 8][col16][j8], elem (c=k8*8+j, o=nt*16+col)
    for (int i = tid; i < 16384; i += 256) {
        int nt = i >> 10, rem = i & 1023;
        int k8 = rem >> 7, col = (rem >> 3) & 15, j = rem & 7;
        int c = k8*8 + j, o = nt*16 + col;
        w1f[i] = f2bf(fc1_w[o*64 + c] * s2s[c]);
    }
    // W2 bf16 fragment order: [nt4][k8 32][col16][j8], elem (c=k8*8+j, o=nt*16+col)
    for (int i = tid; i < 16384; i += 256) {
        int nt = i >> 12, rem = i & 4095;
        int k8 = rem >> 7, col = (rem >> 3) & 15, j = rem & 7;
        int c = k8*8 + j, o = nt*16 + col;
        w2f[i] = f2bf(fc2_w[o*256 + c] * s3s[c]);
    }
    // dw weights padded [ch][12]
    for (int i = tid; i < 3072; i += 256) {
        int ch = i / 12, j = i - (i/12)*12;
        dwp[i] = (j < 9) ? dw_w[ch*9 + j] : 0.f;
    }
}

// Fused: gate(x) -> qkv -> window attention -> hp + shortcut -> s1
__global__ __launch_bounds__(256, 4) void k2_attn(
    const float* __restrict__ x,
    const float* __restrict__ pa_w, const float* __restrict__ pa_b,
    const float* __restrict__ hp_w, const float* __restrict__ hp_b,
    const float* __restrict__ wsw, float* __restrict__ s1out)
{
    __shared__ __align__(16) float regionA[4352];
    __shared__ __align__(16) float gl[4352];   // gated x, [n px][68 ch-stride]
    uint16_t* xs = (uint16_t*)regionA;
    float* paw = regionA + 3264;
    float* pab = regionA + 3840;
    float* att = regionA;

    int tid = threadIdx.x;
    int wid = blockIdx.x;
    int b = wid >> 12;
    int r = wid & 4095;
    int wy = r >> 6, wx = r & 63;
    int y0 = wy*8 - 1, x0 = wx*8 - 1;
    const float* xb = x + (size_t)b * CH * HW;

    for (int i = tid; i < 6400; i += 256) {
        int c = i / 100, p = i - c*100;
        int py = p / 10, px = p - py*10;
        int yy = y0 + py, xx = x0 + px;
        float v = 0.f;
        if (yy >= 0 && yy < HH && xx >= 0 && xx < WW)
            v = xb[(size_t)c*HW + yy*WW + xx];
        xs[c*102 + p] = f2bf(v);
    }
    for (int i = tid; i < 576; i += 256) paw[i] = pa_w[i];
    if (tid < 64) pab[tid] = pa_b[tid];
    __syncthreads();

    for (int i = tid; i < 4096; i += 256) {
        int c = i & 63, n = i >> 6;
        int yy = n >> 3, xx = n & 7;
        const uint16_t* xc = xs + c*102;
        float conv = pab[c];
        #pragma unroll
        for (int dy = 0; dy < 3; dy++)
            #pragma unroll
            for (int dx = 0; dx < 3; dx++)
                conv += bf2f(xc[(yy+dy)*10 + xx+dx]) * paw[c*9 + dy*3 + dx];
        float xv = bf2f(xc[(yy+1)*10 + xx+1]);
        gl[n*68 + c] = xv / (1.f + expf(-conv));
    }
    __syncthreads();

    const float* qw = wsw;
    const float* qb = qw + 2048;
    const float* kw = qb + 32;
    const float* kb = kw + 2048;
    const float* vw = kb + 32;
    const float* vb = vw + 4096;

    int hd = tid >> 4, l = tid & 15;
    const float* wr0 = qw + (hd*2  )*64;
    const float* wr1 = qw + (hd*2+1)*64;
    const float* wr2 = kw + (hd*2  )*64;
    const float* wr3 = kw + (hd*2+1)*64;
    const float* wr4 = vw + (hd*4  )*64;
    const float* wr5 = vw + (hd*4+1)*64;
    const float* wr6 = vw + (hd*4+2)*64;
    const float* wr7 = vw + (hd*4+3)*64;

    float a0[4], a1[4], a2[4], a3[4], a4[4], a5[4], a6[4], a7[4];
    {
        float b0 = qb[hd*2], b1 = qb[hd*2+1], b2 = kb[hd*2], b3 = kb[hd*2+1];
        float b4 = vb[hd*4], b5 = vb[hd*4+1], b6 = vb[hd*4+2], b7 = vb[hd*4+3];
        #pragma unroll
        for (int j = 0; j < 4; j++) {
            a0[j]=b0; a1[j]=b1; a2[j]=b2; a3[j]=b3;
            a4[j]=b4; a5[j]=b5; a6[j]=b6; a7[j]=b7;
        }
    }
    for (int cc = 0; cc < 16; cc++) {
        float4 g0 = *(const float4*)&gl[(l    )*68 + cc*4];
        float4 g1 = *(const float4*)&gl[(l+16)*68 + cc*4];
        float4 g2 = *(const float4*)&gl[(l+32)*68 + cc*4];
        float4 g3 = *(const float4*)&gl[(l+48)*68 + cc*4];
        float4 w;
#define PROJ_ROW(AR, WP) \
        w = *(const float4*)&WP[cc*4]; \
        AR[0] += w.x*g0.x + w.y*g0.y + w.z*g0.z + w.w*g0.w; \
        AR[1] += w.x*g1.x + w.y*g1.y + w.z*g1.z + w.w*g1.w; \
        AR[2] += w.x*g2.x + w.y*g2.y + w.z*g2.z + w.w*g2.w; \
        AR[3] += w.x*g3.x + w.y*g3.y + w.z*g3.z + w.w*g3.w;
        PROJ_ROW(a0, wr0) PROJ_ROW(a1, wr1) PROJ_ROW(a2, wr2) PROJ_ROW(a3, wr3)
        PROJ_ROW(a4, wr4) PROJ_ROW(a5, wr5) PROJ_ROW(a6, wr6) PROJ_ROW(a7, wr7)
#undef PROJ_ROW
    }

    #pragma unroll
    for (int j = 0; j < 4; j++) {
        float m = fmaxf(a0[j], a1[j]);
        float e0 = expf(a0[j]-m), e1 = expf(a1[j]-m);
        float inv = 1.f/(e0+e1);
        a0[j] = e0*inv; a1[j] = e1*inv;
    }
    float m0 = fmaxf(fmaxf(a2[0],a2[1]), fmaxf(a2[2],a2[3]));
    float m1 = fmaxf(fmaxf(a3[0],a3[1]), fmaxf(a3[2],a3[3]));
    #pragma unroll
    for (int s = 1; s < 16; s <<= 1) {
        m0 = fmaxf(m0, __shfl_xor(m0, s, 64));
        m1 = fmaxf(m1, __shfl_xor(m1, s, 64));
    }
    float sum0 = 0.f, sum1 = 0.f;
    #pragma unroll
    for (int j = 0; j < 4; j++) {
        a2[j] = expf(a2[j]-m0); a3[j] = expf(a3[j]-m1);
        sum0 += a2[j]; sum1 += a3[j];
    }
    #pragma unroll
    for (int s = 1; s < 16; s <<= 1) {
        sum0 += __shfl_xor(sum0, s, 64);
        sum1 += __shfl_xor(sum1, s, 64);
    }
    float iv0 = 1.f/sum0, iv1 = 1.f/sum1;
    #pragma unroll
    for (int j = 0; j < 4; j++) { a2[j] *= iv0; a3[j] *= iv1; }
    float ctx0[4], ctx1[4];
    #pragma unroll
    for (int e = 0; e < 4; e++) {
        float ve0, ve1, ve2, ve3;
        if (e==0) { ve0=a4[0]; ve1=a4[1]; ve2=a4[2]; ve3=a4[3]; }
        else if (e==1) { ve0=a5[0]; ve1=a5[1]; ve2=a5[2]; ve3=a5[3]; }
        else if (e==2) { ve0=a6[0]; ve1=a6[1]; ve2=a6[2]; ve3=a6[3]; }
        else { ve0=a7[0]; ve1=a7[1]; ve2=a7[2]; ve3=a7[3]; }
        float c0 = a2[0]*ve0 + a2[1]*ve1 + a2[2]*ve2 + a2[3]*ve3;
        float c1 = a3[0]*ve0 + a3[1]*ve1 + a3[2]*ve2 + a3[3]*ve3;
        #pragma unroll
        for (int s = 1; s < 16; s <<= 1) {
            c0 += __shfl_xor(c0, s, 64);
            c1 += __shfl_xor(c1, s, 64);
        }
        ctx0[e] = c0; ctx1[e] = c1;
    }
    float p00=0.f, p01=0.f, p10=0.f, p11=0.f;
    #pragma unroll
    for (int j = 0; j < 4; j++) {
        p00 += a0[j]*a2[j]; p01 += a0[j]*a3[j];
        p10 += a1[j]*a2[j]; p11 += a1[j]*a3[j];
    }
    #pragma unroll
    for (int s = 1; s < 16; s <<= 1) {
        p00 += __shfl_xor(p00, s, 64); p01 += __shfl_xor(p01, s, 64);
        p10 += __shfl_xor(p10, s, 64); p11 += __shfl_xor(p11, s, 64);
    }
    const float CH_SCALE = 0.70710678118654752f;
    p00 *= CH_SCALE; p01 *= CH_SCALE; p10 *= CH_SCALE; p11 *= CH_SCALE;
    float dc = fmaxf(fmaxf(p00,p01), fmaxf(p10,p11)) + 0.25f*(p00+p01+p10+p11);

    #pragma unroll
    for (int j = 0; j < 4; j++) {
        int n = l + 16*j;
        att[(hd*4+0)*68 + n] = (a0[j]*ctx0[0] + a1[j]*ctx1[0]) * dc;
        att[(hd*4+1)*68 + n] = (a0[j]*ctx0[1] + a1[j]*ctx1[1]) * dc;
        att[(hd*4+2)*68 + n] = (a0[j]*ctx0[2] + a1[j]*ctx1[2]) * dc;
        att[(hd*4+3)*68 + n] = (a0[j]*ctx0[3] + a1[j]*ctx1[3]) * dc;
    }
    __syncthreads();

    int p = tid & 63, co = tid >> 6;
    float oa[16];
    #pragma unroll
    for (int i = 0; i < 16; i++) oa[i] = hp_b[co*16+i];
    for (int cc = 0; cc < 16; cc++) {
        float av0 = att[(cc*4+0)*68 + p];
        float av1 = att[(cc*4+1)*68 + p];
        float av2 = att[(cc*4+2)*68 + p];
        float av3 = att[(cc*4+3)*68 + p];
        #pragma unroll
        for (int i = 0; i < 16; i++) {
            float4 w = *(const float4*)&hp_w[(co*16+i)*64 + cc*4];
            oa[i] += w.x*av0 + w.y*av1 + w.z*av2 + w.w*av3;
        }
    }
    int yy = wy*8 + (p >> 3), xx = wx*8 + (p & 7);
    size_t base = (size_t)b * CH * HW + (size_t)yy * WW + xx;
    #pragma unroll
    for (int i4 = 0; i4 < 4; i4++) {
        float4 g = *(const float4*)&gl[p*68 + co*16 + i4*4];
        s1out[base + (size_t)(co*16+i4*4+0)*HW] = oa[i4*4+0] + g.x;
        s1out[base + (size_t)(co*16+i4*4+1)*HW] = oa[i4*4+1] + g.y;
        s1out[base + (size_t)(co*16+i4*4+2)*HW] = oa[i4*4+2] + g.z;
        s1out[base + (size_t)(co*16+i4*4+3)*HW] = oa[i4*4+3] + g.w;
    }
}

// fc1 (MFMA) + GELU -> h bf16, pair-interleaved NHWC:
// h elem idx = (px>>1)*512 + out*2 + (px&1)
__global__ __launch_bounds__(256) void k3_fc1(
    const float* __restrict__ s1, const float* __restrict__ wsw,
    uint32_t* __restrict__ h32)
{
    __shared__ __align__(16) uint32_t Al[4096];  // A fragments [mt8][k8 8][col16][j8]
    const float* f1b = wsw + 24704;
    const uint16_t* w1f = (const uint16_t*)(wsw + 44480);
    int tid = threadIdx.x;
    int pxbase = blockIdx.x * 128;
    int b = pxbase >> 18;
    int sp = pxbase & (HW - 1);
    {
        int px = tid & 127, chalf = tid >> 7;
        size_t sb = (size_t)b * CH * HW + sp + px;
        #pragma unroll
        for (int i = 0; i < 16; i++) {
            int c = chalf * 32 + i * 2;
            float f0 = s1[sb + (size_t)c * HW];
            float f1 = s1[sb + (size_t)(c + 1) * HW];
            uint32_t pk = (uint32_t)f2bf(f0) | ((uint32_t)f2bf(f1) << 16);
            Al[(((px >> 4) * 128 + (c >> 3) * 16 + (px & 15)) * 8 + (c & 7)) >> 1] = pk;
        }
    }
    __syncthreads();
    int wave = tid >> 6, l = tid & 63;
    f32x4 acc[2][16];
    #pragma unroll
    for (int nt = 0; nt < 16; nt++) {
        float bias = f1b[nt * 16 + (l & 15)];
        acc[0][nt] = {bias, bias, bias, bias};
        acc[1][nt] = acc[0][nt];
    }
    #pragma unroll
    for (int kb = 0; kb < 2; kb++) {
        short8 a0 = *reinterpret_cast<const short8*>(&Al[((wave*2+0)*128 + kb*64 + l) * 4]);
        short8 a1 = *reinterpret_cast<const short8*>(&Al[((wave*2+1)*128 + kb*64 + l) * 4]);
        #pragma unroll
        for (int nt = 0; nt < 16; nt++) {
            short8 bfr = *reinterpret_cast<const short8*>(w1f + (size_t)(nt*128 + kb*64 + l) * 8);
            acc[0][nt] = __builtin_amdgcn_mfma_f32_16x16x32_bf16(a0, bfr, acc[0][nt], 0, 0, 0);
            acc[1][nt] = __builtin_amdgcn_mfma_f32_16x16x32_bf16(a1, bfr, acc[1][nt], 0, 0, 0);
        }
    }
    #pragma unroll
    for (int mt = 0; mt < 2; mt++) {
        int px0 = pxbase + wave*32 + mt*16 + (l >> 4) * 4;
        size_t base = (size_t)(px0 >> 1) * 256;
        #pragma unroll
        for (int nt = 0; nt < 16; nt++) {
            int o = nt*16 + (l & 15);
            float g0 = gelu_f(acc[mt][nt][0]);
            float g1 = gelu_f(acc[mt][nt][1]);
            float g2 = gelu_f(acc[mt][nt][2]);
            float g3 = gelu_f(acc[mt][nt][3]);
            h32[base + o]       = (uint32_t)f2bf(g0) | ((uint32_t)f2bf(g1) << 16);
            h32[base + 256 + o] = (uint32_t)f2bf(g2) | ((uint32_t)f2bf(g3) << 16);
        }
    }
}

// dwconv3 (bn3 folded) + fc2 (MFMA) + residual -> out
__global__ __launch_bounds__(256) void k4_mlp2(
    const uint32_t* __restrict__ h32, const float* __restrict__ wsw,
    const float* __restrict__ s1, float* __restrict__ out)
{
    __shared__ __align__(16) uint16_t hl[18*20*72];   // halo [hy18][hx20][72-pad ch]
    const float* f2b = wsw + 41344;
    const float* dwp = wsw + 41408;
    const uint16_t* w2f = (const uint16_t*)(wsw + 52672);
    int tid = threadIdx.x;
    int wave = tid >> 6, l = tid & 63;
    int tile = blockIdx.x;
    int X = (tile & 31) * 16, Y = (tile >> 5) * 16;
    int b = blockIdx.y;
    const uint8_t* hb = (const uint8_t*)h32;

    f32x4 acc[4][4];
    #pragma unroll
    for (int nt = 0; nt < 4; nt++) {
        float bias = f2b[nt*16 + (l & 15)];
        #pragma unroll
        for (int mt = 0; mt < 4; mt++) acc[mt][nt] = {bias, bias, bias, bias};
    }

    for (int cc = 0; cc < 4; cc++) {
        __syncthreads();
        for (int i = tid; i < 2880; i += 256) {
            int g = i & 15, pr = i >> 4;
            int hy = pr / 10, pp = pr - hy*10;
            int yy = Y - 1 + hy, gx0 = X - 2 + pp*2;
            uint4 q = {0u, 0u, 0u, 0u};
            if ((unsigned)yy < 512u && (unsigned)gx0 < 512u) {
                size_t pairidx = ((size_t)b*HW + (size_t)yy*512 + gx0) >> 1;
                q = *reinterpret_cast<const uint4*>(hb + pairidx*1024 + (size_t)(cc*64 + g*4)*4);
            }
            uint32_t A0 = (q.x & 0xffffu) | (q.y << 16);
            uint32_t A1 = (q.z & 0xffffu) | (q.w << 16);
            uint32_t B0 = (q.x >> 16) | (q.y & 0xffff0000u);
            uint32_t B1 = (q.z >> 16) | (q.w & 0xffff0000u);
            int base = (hy*20 + pp*2) * 72 + g*4;
            *reinterpret_cast<uint64_t*>(&hl[base])      = (uint64_t)A0 | ((uint64_t)A1 << 32);
            *reinterpret_cast<uint64_t*>(&hl[base + 72]) = (uint64_t)B0 | ((uint64_t)B1 << 32);
        }
        __syncthreads();

        #pragma unroll
        for (int kb = 0; kb < 2; kb++) {
            int chg = cc*64 + kb*32 + (l >> 4) * 8;
            float w[8][9];
            #pragma unroll
            for (int c8 = 0; c8 < 8; c8++) {
                const float* wp = dwp + (chg + c8) * 12;
                float4 w0 = *(const float4*)(wp);
                float4 w1 = *(const float4*)(wp + 4);
                float4 w2v = *(const float4*)(wp + 8);
                w[c8][0]=w0.x; w[c8][1]=w0.y; w[c8][2]=w0.z; w[c8][3]=w0.w;
                w[c8][4]=w1.x; w[c8][5]=w1.y; w[c8][6]=w1.z; w[c8][7]=w1.w;
                w[c8][8]=w2v.x;
            }
            short8 af[4];
            #pragma unroll
            for (int mt = 0; mt < 4; mt++) {
                int mtg = wave*4 + mt;
                float t0=0.f,t1=0.f,t2=0.f,t3=0.f,t4=0.f,t5=0.f,t6=0.f,t7=0.f;
                #pragma unroll
                for (int dy = 0; dy < 3; dy++) {
                    #pragma unroll
                    for (int dx = 0; dx < 3; dx++) {
                        int byteoff = ((mtg + dy)*20 + (l & 15) + dx + 1)*144
                                      + kb*64 + (l >> 4)*16;
                        uint4 q = *reinterpret_cast<const uint4*>(
                            reinterpret_cast<const uint8_t*>(hl) + byteoff);
                        int wi = dy*3 + dx;
                        t0 += __uint_as_float(q.x << 16)          * w[0][wi];
                        t1 += __uint_as_float(q.x & 0xffff0000u)  * w[1][wi];
                        t2 += __uint_as_float(q.y << 16)          * w[2][wi];
                        t3 += __uint_as_float(q.y & 0xffff0000u)  * w[3][wi];
                        t4 += __uint_as_float(q.z << 16)          * w[4][wi];
                        t5 += __uint_as_float(q.z & 0xffff0000u)  * w[5][wi];
                        t6 += __uint_as_float(q.w << 16)          * w[6][wi];
                        t7 += __uint_as_float(q.w & 0xffff0000u)  * w[7][wi];
                    }
                }
                short8 a;
                a[0]=(short)f2bf(t0); a[1]=(short)f2bf(t1);
                a[2]=(short)f2bf(t2); a[3]=(short)f2bf(t3);
                a[4]=(short)f2bf(t4); a[5]=(short)f2bf(t5);
                a[6]=(short)f2bf(t6); a[7]=(short)f2bf(t7);
                af[mt] = a;
            }
            #pragma unroll
            for (int nt = 0; nt < 4; nt++) {
                short8 bfr = *reinterpret_cast<const short8*>(
                    w2f + (size_t)(nt*512 + cc*128 + kb*64 + l) * 8);
                #pragma unroll
                for (int mt = 0; mt < 4; mt++)
                    acc[mt][nt] = __builtin_amdgcn_mfma_f32_16x16x32_bf16(af[mt], bfr, acc[mt][nt], 0, 0, 0);
            }
        }
    }
    int r0 = (l >> 4) * 4;
    #pragma unroll
    for (int mt = 0; mt < 4; mt++) {
        int mtg = wave*4 + mt;
        #pragma unroll
        for (int nt = 0; nt < 4; nt++) {
            int o = nt*16 + (l & 15);
            size_t idx = ((size_t)b*CH + o)*HW + (size_t)(Y + mtg)*512 + X + r0;
            float4 sv = *reinterpret_cast<const float4*>(s1 + idx);
            float4 ov;
            ov.x = acc[mt][nt][0] + sv.x;
            ov.y = acc[mt][nt][1] + sv.y;
            ov.z = acc[mt][nt][2] + sv.z;
            ov.w = acc[mt][nt][3] + sv.w;
            *reinterpret_cast<float4*>(out + idx) = ov;
        }
    }
}

extern "C" void kernel_launch(void* const* d_in, const int* in_sizes, int n_in,
                              void* d_out, int out_size, void* d_ws, size_t ws_size,
                              hipStream_t stream) {
    const float* x     = (const float*)d_in[0];
    const float* pa_w  = (const float*)d_in[1];
    const float* pa_b  = (const float*)d_in[2];
    const float* bn1_g = (const float*)d_in[3];
    const float* bn1_b = (const float*)d_in[4];
    const float* bn1_m = (const float*)d_in[5];
    const float* bn1_v = (const float*)d_in[6];
    const float* q_w   = (const float*)d_in[7];
    const float* q_b   = (const float*)d_in[8];
    const float* k_w   = (const float*)d_in[9];
    const float* k_b   = (const float*)d_in[10];
    const float* v_w   = (const float*)d_in[11];
    const float* v_b   = (const float*)d_in[12];
    const float* hp_w  = (const float*)d_in[13];
    const float* hp_b  = (const float*)d_in[14];
    const float* bn2_g = (const float*)d_in[15];
    const float* bn2_b = (const float*)d_in[16];
    const float* bn2_m = (const float*)d_in[17];
    const float* bn2_v = (const float*)d_in[18];
    const float* fc1_w = (const float*)d_in[19];
    const float* fc1_b = (const float*)d_in[20];
    const float* dw_w  = (const float*)d_in[21];
    const float* dw_b  = (const float*)d_in[22];
    const float* bn3_g = (const float*)d_in[23];
    const float* bn3_b = (const float*)d_in[24];
    const float* bn3_m = (const float*)d_in[25];
    const float* bn3_v = (const float*)d_in[26];
    const float* fc2_w = (const float*)d_in[27];
    const float* fc2_b = (const float*)d_in[28];

    float*    s1  = (float*)d_ws;                                   // 134,217,728 B
    uint32_t* h32 = (uint32_t*)((char*)d_ws + 134217728);           // 268,435,456 B
    float*    wsw = (float*)((char*)d_ws + 134217728 + 268435456);  // ~244 KB

    k0_fold<<<dim3(1), dim3(256), 0, stream>>>(
        q_w, q_b, k_w, k_b, v_w, v_b,
        bn1_g, bn1_b, bn1_m, bn1_v,
        fc1_w, fc1_b, bn2_g, bn2_b, bn2_m, bn2_v,
        fc2_w, fc2_b, dw_w, dw_b, bn3_g, bn3_b, bn3_m, bn3_v, wsw);

    k2_attn<<<dim3(8192), dim3(256), 0, stream>>>(
        x, pa_w, pa_b, hp_w, hp_b, wsw, s1);

    k3_fc1<<<dim3(4096), dim3(256), 0, stream>>>(s1, wsw, h32);

    k4_mlp2<<<dim3(1024, 2), dim3(256), 0, stream>>>(
        h32, wsw, s1, (float*)d_out);
}

// Round 4
// 1000.470 us; speedup vs baseline: 1.7819x; 1.2228x over previous
//
#include <hip/hip_runtime.h>
#include <stdint.h>

#define HH 512
#define WW 512
#define HW 262144
#define CH 64
#define HID 256

typedef __attribute__((ext_vector_type(8))) short short8;
typedef __attribute__((ext_vector_type(4))) float f32x4;

// ws float-offset layout (after s1 + h byte regions):
#define WS_QKVB 0      // 128 f32  (folded q|k|v bias)
#define WS_F1B  128    // 256 f32
#define WS_F2B  384    // 64 f32
#define WS_DWP  448    // 3072 f32 (dw weights padded [ch][12])
#define WS_W1F  3520   // 16384 u16 (fc1 B-frags)
#define WS_W2F  11712  // 16384 u16 (fc2 B-frags)
#define WS_WQKV 19904  // 8192 u16 (qkv B-frags [nt8][k8 8][col16][j8])
#define WS_WHP  24000  // 4096 u16 (hp  A-frags [mt4][k8 8][row16][j8])

__device__ __forceinline__ float bf2f(uint16_t u) {
    return __uint_as_float(((uint32_t)u) << 16);
}
__device__ __forceinline__ uint16_t f2bf(float f) {
    uint32_t x = __float_as_uint(f);
    uint32_t r = x + 0x7fffu + ((x >> 16) & 1u);
    return (uint16_t)(r >> 16);
}

// fast exact-erf GELU (A&S 7.1.26, |err| < 1.5e-7)
__device__ __forceinline__ float gelu_f(float v) {
    float u = v * 0.70710678118654752f;
    float a = fabsf(u);
    float t = 1.f / (1.f + 0.3275911f * a);
    float p = t*(0.254829592f + t*(-0.284496736f + t*(1.421413741f +
              t*(-1.453152027f + t*1.061405429f))));
    float e = __expf(-u*u);
    float er = copysignf(1.f - p*e, u);
    return 0.5f * v * (1.f + er);
}

__global__ __launch_bounds__(256) void k0_fold(
    const float* __restrict__ q_w, const float* __restrict__ q_b,
    const float* __restrict__ k_w, const float* __restrict__ k_b,
    const float* __restrict__ v_w, const float* __restrict__ v_b,
    const float* __restrict__ bn1_g, const float* __restrict__ bn1_b,
    const float* __restrict__ bn1_m, const float* __restrict__ bn1_v,
    const float* __restrict__ fc1_w, const float* __restrict__ fc1_b,
    const float* __restrict__ bn2_g, const float* __restrict__ bn2_b,
    const float* __restrict__ bn2_m, const float* __restrict__ bn2_v,
    const float* __restrict__ fc2_w, const float* __restrict__ fc2_b,
    const float* __restrict__ hp_w,
    const float* __restrict__ dw_w, const float* __restrict__ dw_b,
    const float* __restrict__ bn3_g, const float* __restrict__ bn3_b,
    const float* __restrict__ bn3_m, const float* __restrict__ bn3_v,
    float* __restrict__ wsw)
{
    __shared__ float s1s[64], t1s[64], s2s[64], t2s[64], s3s[256], t3s[256];
    int tid = threadIdx.x;
    if (tid < 64) {
        float s = bn1_g[tid] * rsqrtf(bn1_v[tid] + 1e-5f);
        s1s[tid] = s; t1s[tid] = bn1_b[tid] - bn1_m[tid] * s;
        float s2 = bn2_g[tid] * rsqrtf(bn2_v[tid] + 1e-5f);
        s2s[tid] = s2; t2s[tid] = bn2_b[tid] - bn2_m[tid] * s2;
    }
    if (tid < 256) {
        float s = bn3_g[tid] * rsqrtf(bn3_v[tid] + 1e-5f);
        s3s[tid] = s;
        t3s[tid] = (dw_b[tid] - bn3_m[tid]) * s + bn3_b[tid];
    }
    __syncthreads();

    float* qkvb = wsw + WS_QKVB;
    float* f1b  = wsw + WS_F1B;
    float* f2b  = wsw + WS_F2B;
    float* dwp  = wsw + WS_DWP;
    uint16_t* w1f   = (uint16_t*)(wsw + WS_W1F);
    uint16_t* w2f   = (uint16_t*)(wsw + WS_W2F);
    uint16_t* wqkvf = (uint16_t*)(wsw + WS_WQKV);
    uint16_t* whpf  = (uint16_t*)(wsw + WS_WHP);

    // folded qkv bias
    if (tid < 128) {
        int o = tid;
        float a;
        if (o < 32) {
            a = q_b[o];
            for (int c = 0; c < 64; c++) a += q_w[o*64+c]*t1s[c];
        } else if (o < 64) {
            a = k_b[o-32];
            for (int c = 0; c < 64; c++) a += k_w[(o-32)*64+c]*t1s[c];
        } else {
            a = v_b[o-64];
            for (int c = 0; c < 64; c++) a += v_w[(o-64)*64+c]*t1s[c];
        }
        qkvb[o] = a;
    }
    if (tid < 256) {
        float a = fc1_b[tid];
        for (int c = 0; c < 64; c++) a += fc1_w[tid*64+c]*t2s[c];
        f1b[tid] = a;
    }
    if (tid < 64) {
        float a = fc2_b[tid];
        for (int c = 0; c < 256; c++) a += fc2_w[tid*256+c]*t3s[c];
        f2b[tid] = a;
    }
    // qkv weight B-frags: [nt8][k8 8][col16][j8]; o=nt*16+col in [q0..31|k0..31|v0..63], c=k8*8+j
    for (int i = tid; i < 8192; i += 256) {
        int nt = i >> 10, rem = i & 1023;
        int k8 = rem >> 7, col = (rem >> 3) & 15, j = rem & 7;
        int o = nt*16 + col, c = k8*8 + j;
        float w;
        if (o < 32)      w = q_w[o*64 + c];
        else if (o < 64) w = k_w[(o-32)*64 + c];
        else             w = v_w[(o-64)*64 + c];
        wqkvf[i] = f2bf(w * s1s[c]);
    }
    // hp weight A-frags: [mt4][k8 8][row16][j8]; o=mt*16+row, c=k8*8+j
    for (int i = tid; i < 4096; i += 256) {
        int mt = i >> 10, rem = i & 1023;
        int k8 = rem >> 7, row = (rem >> 3) & 15, j = rem & 7;
        int o = mt*16 + row, c = k8*8 + j;
        whpf[i] = f2bf(hp_w[o*64 + c]);
    }
    // W1 B-frags: [nt16][k8 8][col16][j8]
    for (int i = tid; i < 16384; i += 256) {
        int nt = i >> 10, rem = i & 1023;
        int k8 = rem >> 7, col = (rem >> 3) & 15, j = rem & 7;
        int c = k8*8 + j, o = nt*16 + col;
        w1f[i] = f2bf(fc1_w[o*64 + c] * s2s[c]);
    }
    // W2 B-frags: [nt4][k8 32][col16][j8]
    for (int i = tid; i < 16384; i += 256) {
        int nt = i >> 12, rem = i & 4095;
        int k8 = rem >> 7, col = (rem >> 3) & 15, j = rem & 7;
        int c = k8*8 + j, o = nt*16 + col;
        w2f[i] = f2bf(fc2_w[o*256 + c] * s3s[c]);
    }
    // dw weights padded [ch][12]
    for (int i = tid; i < 3072; i += 256) {
        int ch = i / 12, j = i - (i/12)*12;
        dwp[i] = (j < 9) ? dw_w[ch*9 + j] : 0.f;
    }
}

// Fused: gate(x) -> qkv (MFMA) -> window attention -> hp (MFMA) + shortcut -> s1
// one block per 8x8 window; 4 waves. LDS 51.7KB -> 3 blocks/CU.
__global__ __launch_bounds__(256, 3) void k2_attn(
    const float* __restrict__ x,
    const float* __restrict__ pa_w, const float* __restrict__ pa_b,
    const float* __restrict__ hp_b,
    const float* __restrict__ wsw, float* __restrict__ s1out)
{
    // qkvl region: phase 1-2 = halo f32 [64][103] + paw/pab; phase 3+ = qkv [128][69] f32
    __shared__ __align__(16) float qkvl[8832];
    __shared__ __align__(16) uint16_t gfrag[4096];  // gated-x A/B-frags [t4][k8 8][idx16][j8]
    __shared__ __align__(16) uint16_t afrag[4096];  // att B-frags for hp
    float* xs  = qkvl;            // [64][103]
    float* paw = qkvl + 6592;     // 576
    float* pab = qkvl + 7168;     // 64

    int tid = threadIdx.x;
    int wave = tid >> 6, l = tid & 63;
    int wid = blockIdx.x;
    int b = wid >> 12;
    int r = wid & 4095;
    int wy = r >> 6, wx = r & 63;
    int y0 = wy*8 - 1, x0 = wx*8 - 1;
    const float* xb = x + (size_t)b * CH * HW;

    // ---- phase 1: halo load ----
    for (int i = tid; i < 6400; i += 256) {
        int c = i / 100, p = i - c*100;
        int py = p / 10, px = p - py*10;
        int yy = y0 + py, xx = x0 + px;
        float v = 0.f;
        if (yy >= 0 && yy < HH && xx >= 0 && xx < WW)
            v = xb[(size_t)c*HW + yy*WW + xx];
        xs[c*103 + p] = v;
    }
    for (int i = tid; i < 576; i += 256) paw[i] = pa_w[i];
    if (tid < 64) pab[tid] = pa_b[tid];
    __syncthreads();

    // ---- phase 2: gate -> gfrag (bf16 fragments [n>>4][c>>3][n&15][c&7]) ----
    for (int i = tid; i < 4096; i += 256) {
        int c = i & 63, n = i >> 6;
        int yy = n >> 3, xx = n & 7;
        const float* xc = xs + c*103;
        float conv = pab[c];
        #pragma unroll
        for (int dy = 0; dy < 3; dy++)
            #pragma unroll
            for (int dx = 0; dx < 3; dx++)
                conv += xc[(yy+dy)*10 + xx+dx] * paw[c*9 + dy*3 + dx];
        float xv = xc[(yy+1)*10 + xx+1];
        float gv = xv / (1.f + expf(-conv));
        gfrag[(n>>4)*1024 + (c>>3)*128 + (n&15)*8 + (c&7)] = f2bf(gv);
    }
    __syncthreads();   // gfrag ready; xs/paw dead -> qkvl reusable

    // ---- phase 3: qkv MFMA: [64px x 64ch] * [64ch x 128out] -> qkvl[out][69]+px ----
    {
        const uint16_t* wqkv = (const uint16_t*)(wsw + WS_WQKV);
        const float* qkvb = wsw + WS_QKVB;
        f32x4 acc[4][2];
        #pragma unroll
        for (int ntw = 0; ntw < 2; ntw++) {
            float bias = qkvb[(wave*2+ntw)*16 + (l & 15)];
            #pragma unroll
            for (int mt = 0; mt < 4; mt++) acc[mt][ntw] = {bias, bias, bias, bias};
        }
        #pragma unroll
        for (int kb = 0; kb < 2; kb++) {
            short8 a[4];
            #pragma unroll
            for (int mt = 0; mt < 4; mt++)
                a[mt] = *reinterpret_cast<const short8*>(&gfrag[mt*1024 + kb*512 + 8*l]);
            #pragma unroll
            for (int ntw = 0; ntw < 2; ntw++) {
                int nt = wave*2 + ntw;
                short8 bf = *reinterpret_cast<const short8*>(&wqkv[nt*1024 + kb*512 + 8*l]);
                #pragma unroll
                for (int mt = 0; mt < 4; mt++)
                    acc[mt][ntw] = __builtin_amdgcn_mfma_f32_16x16x32_bf16(a[mt], bf, acc[mt][ntw], 0, 0, 0);
            }
        }
        __syncthreads();   // xs reads done (phase2 barrier) -- safe to overwrite qkvl
        #pragma unroll
        for (int ntw = 0; ntw < 2; ntw++) {
            int o = (wave*2+ntw)*16 + (l & 15);
            #pragma unroll
            for (int mt = 0; mt < 4; mt++) {
                int px0 = mt*16 + (l >> 4)*4;
                #pragma unroll
                for (int rr = 0; rr < 4; rr++)
                    qkvl[o*69 + px0 + rr] = acc[mt][ntw][rr];
            }
        }
    }
    __syncthreads();

    // ---- phase 4: attention (shuffle math within 16-lane head groups) ----
    {
        int hd = tid >> 4, l16 = tid & 15;
        float a0[4], a1[4], a2[4], a3[4], a4[4], a5[4], a6[4], a7[4];
        #pragma unroll
        for (int j = 0; j < 4; j++) {
            int px = l16 + 16*j;
            a0[j] = qkvl[(2*hd    )*69 + px];
            a1[j] = qkvl[(2*hd + 1)*69 + px];
            a2[j] = qkvl[(32 + 2*hd    )*69 + px];
            a3[j] = qkvl[(32 + 2*hd + 1)*69 + px];
            a4[j] = qkvl[(64 + 4*hd    )*69 + px];
            a5[j] = qkvl[(64 + 4*hd + 1)*69 + px];
            a6[j] = qkvl[(64 + 4*hd + 2)*69 + px];
            a7[j] = qkvl[(64 + 4*hd + 3)*69 + px];
        }
        #pragma unroll
        for (int j = 0; j < 4; j++) {
            float m = fmaxf(a0[j], a1[j]);
            float e0 = expf(a0[j]-m), e1 = expf(a1[j]-m);
            float inv = 1.f/(e0+e1);
            a0[j] = e0*inv; a1[j] = e1*inv;
        }
        float m0 = fmaxf(fmaxf(a2[0],a2[1]), fmaxf(a2[2],a2[3]));
        float m1 = fmaxf(fmaxf(a3[0],a3[1]), fmaxf(a3[2],a3[3]));
        #pragma unroll
        for (int s = 1; s < 16; s <<= 1) {
            m0 = fmaxf(m0, __shfl_xor(m0, s, 64));
            m1 = fmaxf(m1, __shfl_xor(m1, s, 64));
        }
        float sum0 = 0.f, sum1 = 0.f;
        #pragma unroll
        for (int j = 0; j < 4; j++) {
            a2[j] = expf(a2[j]-m0); a3[j] = expf(a3[j]-m1);
            sum0 += a2[j]; sum1 += a3[j];
        }
        #pragma unroll
        for (int s = 1; s < 16; s <<= 1) {
            sum0 += __shfl_xor(sum0, s, 64);
            sum1 += __shfl_xor(sum1, s, 64);
        }
        float iv0 = 1.f/sum0, iv1 = 1.f/sum1;
        #pragma unroll
        for (int j = 0; j < 4; j++) { a2[j] *= iv0; a3[j] *= iv1; }
        float ctx0[4], ctx1[4];
        #pragma unroll
        for (int e = 0; e < 4; e++) {
            float ve0, ve1, ve2, ve3;
            if (e==0) { ve0=a4[0]; ve1=a4[1]; ve2=a4[2]; ve3=a4[3]; }
            else if (e==1) { ve0=a5[0]; ve1=a5[1]; ve2=a5[2]; ve3=a5[3]; }
            else if (e==2) { ve0=a6[0]; ve1=a6[1]; ve2=a6[2]; ve3=a6[3]; }
            else { ve0=a7[0]; ve1=a7[1]; ve2=a7[2]; ve3=a7[3]; }
            float c0 = a2[0]*ve0 + a2[1]*ve1 + a2[2]*ve2 + a2[3]*ve3;
            float c1 = a3[0]*ve0 + a3[1]*ve1 + a3[2]*ve2 + a3[3]*ve3;
            #pragma unroll
            for (int s = 1; s < 16; s <<= 1) {
                c0 += __shfl_xor(c0, s, 64);
                c1 += __shfl_xor(c1, s, 64);
            }
            ctx0[e] = c0; ctx1[e] = c1;
        }
        float p00=0.f, p01=0.f, p10=0.f, p11=0.f;
        #pragma unroll
        for (int j = 0; j < 4; j++) {
            p00 += a0[j]*a2[j]; p01 += a0[j]*a3[j];
            p10 += a1[j]*a2[j]; p11 += a1[j]*a3[j];
        }
        #pragma unroll
        for (int s = 1; s < 16; s <<= 1) {
            p00 += __shfl_xor(p00, s, 64); p01 += __shfl_xor(p01, s, 64);
            p10 += __shfl_xor(p10, s, 64); p11 += __shfl_xor(p11, s, 64);
        }
        const float CH_SCALE = 0.70710678118654752f;
        p00 *= CH_SCALE; p01 *= CH_SCALE; p10 *= CH_SCALE; p11 *= CH_SCALE;
        float dc = fmaxf(fmaxf(p00,p01), fmaxf(p10,p11)) + 0.25f*(p00+p01+p10+p11);

        // att -> B-frags: afrag[(n>>4)*1024 + (c>>3)*128 + (n&15)*8 + (c&7)], c = hd*4+e
        #pragma unroll
        for (int j = 0; j < 4; j++) {
            uint16_t t[4];
            #pragma unroll
            for (int e = 0; e < 4; e++)
                t[e] = f2bf((a0[j]*ctx0[e] + a1[j]*ctx1[e]) * dc);
            *reinterpret_cast<uint64_t*>(
                &afrag[j*1024 + (hd>>1)*128 + l16*8 + (hd&1)*4]) =
                *reinterpret_cast<const uint64_t*>(t);
        }
    }
    __syncthreads();

    // ---- phase 5+6: hp MFMA (D[o][px] = hp_w * att^T) + bias + shortcut -> s1 ----
    {
        const uint16_t* whp = (const uint16_t*)(wsw + WS_WHP);
        int nt = wave;   // px tile
        f32x4 oacc[4];
        #pragma unroll
        for (int mt = 0; mt < 4; mt++) {
            int o0 = mt*16 + (l >> 4)*4;
            oacc[mt] = {hp_b[o0], hp_b[o0+1], hp_b[o0+2], hp_b[o0+3]};
        }
        #pragma unroll
        for (int kb = 0; kb < 2; kb++) {
            short8 bf = *reinterpret_cast<const short8*>(&afrag[nt*1024 + kb*512 + 8*l]);
            #pragma unroll
            for (int mt = 0; mt < 4; mt++) {
                short8 a = *reinterpret_cast<const short8*>(&whp[mt*1024 + kb*512 + 8*l]);
                oacc[mt] = __builtin_amdgcn_mfma_f32_16x16x32_bf16(a, bf, oacc[mt], 0, 0, 0);
            }
        }
        int px = nt*16 + (l & 15);
        int yy = wy*8 + (px >> 3), xx = wx*8 + (px & 7);
        size_t pbase = (size_t)b * CH * HW + (size_t)yy * WW + xx;
        #pragma unroll
        for (int mt = 0; mt < 4; mt++) {
            #pragma unroll
            for (int rr = 0; rr < 4; rr++) {
                int o = mt*16 + (l >> 4)*4 + rr;
                float g = bf2f(gfrag[(px>>4)*1024 + (o>>3)*128 + (px&15)*8 + (o&7)]);
                s1out[pbase + (size_t)o * HW] = oacc[mt][rr] + g;
            }
        }
    }
}

// fc1 (MFMA) + GELU -> h bf16, pair-interleaved NHWC:
// h elem idx = (px>>1)*512 + out*2 + (px&1)
__global__ __launch_bounds__(256) void k3_fc1(
    const float* __restrict__ s1, const float* __restrict__ wsw,
    uint32_t* __restrict__ h32)
{
    __shared__ __align__(16) uint32_t Al[4096];  // A fragments [mt8][k8 8][col16][j8]
    const float* f1b = wsw + WS_F1B;
    const uint16_t* w1f = (const uint16_t*)(wsw + WS_W1F);
    int tid = threadIdx.x;
    int pxbase = blockIdx.x * 128;
    int b = pxbase >> 18;
    int sp = pxbase & (HW - 1);
    {
        int px = tid & 127, chalf = tid >> 7;
        size_t sb = (size_t)b * CH * HW + sp + px;
        #pragma unroll
        for (int i = 0; i < 16; i++) {
            int c = chalf * 32 + i * 2;
            float f0 = s1[sb + (size_t)c * HW];
            float f1 = s1[sb + (size_t)(c + 1) * HW];
            uint32_t pk = (uint32_t)f2bf(f0) | ((uint32_t)f2bf(f1) << 16);
            Al[(((px >> 4) * 128 + (c >> 3) * 16 + (px & 15)) * 8 + (c & 7)) >> 1] = pk;
        }
    }
    __syncthreads();
    int wave = tid >> 6, l = tid & 63;
    f32x4 acc[2][16];
    #pragma unroll
    for (int nt = 0; nt < 16; nt++) {
        float bias = f1b[nt * 16 + (l & 15)];
        acc[0][nt] = {bias, bias, bias, bias};
        acc[1][nt] = acc[0][nt];
    }
    #pragma unroll
    for (int kb = 0; kb < 2; kb++) {
        short8 a0 = *reinterpret_cast<const short8*>(&Al[((wave*2+0)*128 + kb*64 + l) * 4]);
        short8 a1 = *reinterpret_cast<const short8*>(&Al[((wave*2+1)*128 + kb*64 + l) * 4]);
        #pragma unroll
        for (int nt = 0; nt < 16; nt++) {
            short8 bfr = *reinterpret_cast<const short8*>(w1f + (size_t)(nt*128 + kb*64 + l) * 8);
            acc[0][nt] = __builtin_amdgcn_mfma_f32_16x16x32_bf16(a0, bfr, acc[0][nt], 0, 0, 0);
            acc[1][nt] = __builtin_amdgcn_mfma_f32_16x16x32_bf16(a1, bfr, acc[1][nt], 0, 0, 0);
        }
    }
    #pragma unroll
    for (int mt = 0; mt < 2; mt++) {
        int px0 = pxbase + wave*32 + mt*16 + (l >> 4) * 4;
        size_t base = (size_t)(px0 >> 1) * 256;
        #pragma unroll
        for (int nt = 0; nt < 16; nt++) {
            int o = nt*16 + (l & 15);
            float g0 = gelu_f(acc[mt][nt][0]);
            float g1 = gelu_f(acc[mt][nt][1]);
            float g2 = gelu_f(acc[mt][nt][2]);
            float g3 = gelu_f(acc[mt][nt][3]);
            h32[base + o]       = (uint32_t)f2bf(g0) | ((uint32_t)f2bf(g1) << 16);
            h32[base + 256 + o] = (uint32_t)f2bf(g2) | ((uint32_t)f2bf(g3) << 16);
        }
    }
}

// dwconv3 (bn3 folded) + fc2 (MFMA) + residual -> out
__global__ __launch_bounds__(256) void k4_mlp2(
    const uint32_t* __restrict__ h32, const float* __restrict__ wsw,
    const float* __restrict__ s1, float* __restrict__ out)
{
    __shared__ __align__(16) uint16_t hl[18*20*72];   // halo [hy18][hx20][72-pad ch]
    const float* f2b = wsw + WS_F2B;
    const float* dwp = wsw + WS_DWP;
    const uint16_t* w2f = (const uint16_t*)(wsw + WS_W2F);
    int tid = threadIdx.x;
    int wave = tid >> 6, l = tid & 63;
    int tile = blockIdx.x;
    int X = (tile & 31) * 16, Y = (tile >> 5) * 16;
    int b = blockIdx.y;
    const uint8_t* hb = (const uint8_t*)h32;

    f32x4 acc[4][4];
    #pragma unroll
    for (int nt = 0; nt < 4; nt++) {
        float bias = f2b[nt*16 + (l & 15)];
        #pragma unroll
        for (int mt = 0; mt < 4; mt++) acc[mt][nt] = {bias, bias, bias, bias};
    }

    for (int cc = 0; cc < 4; cc++) {
        __syncthreads();
        for (int i = tid; i < 2880; i += 256) {
            int g = i & 15, pr = i >> 4;
            int hy = pr / 10, pp = pr - hy*10;
            int yy = Y - 1 + hy, gx0 = X - 2 + pp*2;
            uint4 q = {0u, 0u, 0u, 0u};
            if ((unsigned)yy < 512u && (unsigned)gx0 < 512u) {
                size_t pairidx = ((size_t)b*HW + (size_t)yy*512 + gx0) >> 1;
                q = *reinterpret_cast<const uint4*>(hb + pairidx*1024 + (size_t)(cc*64 + g*4)*4);
            }
            uint32_t A0 = (q.x & 0xffffu) | (q.y << 16);
            uint32_t A1 = (q.z & 0xffffu) | (q.w << 16);
            uint32_t B0 = (q.x >> 16) | (q.y & 0xffff0000u);
            uint32_t B1 = (q.z >> 16) | (q.w & 0xffff0000u);
            int base = (hy*20 + pp*2) * 72 + g*4;
            *reinterpret_cast<uint64_t*>(&hl[base])      = (uint64_t)A0 | ((uint64_t)A1 << 32);
            *reinterpret_cast<uint64_t*>(&hl[base + 72]) = (uint64_t)B0 | ((uint64_t)B1 << 32);
        }
        __syncthreads();

        #pragma unroll
        for (int kb = 0; kb < 2; kb++) {
            int chg = cc*64 + kb*32 + (l >> 4) * 8;
            float w[8][9];
            #pragma unroll
            for (int c8 = 0; c8 < 8; c8++) {
                const float* wp = dwp + (chg + c8) * 12;
                float4 w0 = *(const float4*)(wp);
                float4 w1 = *(const float4*)(wp + 4);
                float4 w2v = *(const float4*)(wp + 8);
                w[c8][0]=w0.x; w[c8][1]=w0.y; w[c8][2]=w0.z; w[c8][3]=w0.w;
                w[c8][4]=w1.x; w[c8][5]=w1.y; w[c8][6]=w1.z; w[c8][7]=w1.w;
                w[c8][8]=w2v.x;
            }
            short8 af[4];
            #pragma unroll
            for (int mt = 0; mt < 4; mt++) {
                int mtg = wave*4 + mt;
                float t0=0.f,t1=0.f,t2=0.f,t3=0.f,t4=0.f,t5=0.f,t6=0.f,t7=0.f;
                #pragma unroll
                for (int dy = 0; dy < 3; dy++) {
                    #pragma unroll
                    for (int dx = 0; dx < 3; dx++) {
                        int byteoff = ((mtg + dy)*20 + (l & 15) + dx + 1)*144
                                      + kb*64 + (l >> 4)*16;
                        uint4 q = *reinterpret_cast<const uint4*>(
                            reinterpret_cast<const uint8_t*>(hl) + byteoff);
                        int wi = dy*3 + dx;
                        t0 += __uint_as_float(q.x << 16)          * w[0][wi];
                        t1 += __uint_as_float(q.x & 0xffff0000u)  * w[1][wi];
                        t2 += __uint_as_float(q.y << 16)          * w[2][wi];
                        t3 += __uint_as_float(q.y & 0xffff0000u)  * w[3][wi];
                        t4 += __uint_as_float(q.z << 16)          * w[4][wi];
                        t5 += __uint_as_float(q.z & 0xffff0000u)  * w[5][wi];
                        t6 += __uint_as_float(q.w << 16)          * w[6][wi];
                        t7 += __uint_as_float(q.w & 0xffff0000u)  * w[7][wi];
                    }
                }
                short8 a;
                a[0]=(short)f2bf(t0); a[1]=(short)f2bf(t1);
                a[2]=(short)f2bf(t2); a[3]=(short)f2bf(t3);
                a[4]=(short)f2bf(t4); a[5]=(short)f2bf(t5);
                a[6]=(short)f2bf(t6); a[7]=(short)f2bf(t7);
                af[mt] = a;
            }
            #pragma unroll
            for (int nt = 0; nt < 4; nt++) {
                short8 bfr = *reinterpret_cast<const short8*>(
                    w2f + (size_t)(nt*512 + cc*128 + kb*64 + l) * 8);
                #pragma unroll
                for (int mt = 0; mt < 4; mt++)
                    acc[mt][nt] = __builtin_amdgcn_mfma_f32_16x16x32_bf16(af[mt], bfr, acc[mt][nt], 0, 0, 0);
            }
        }
    }
    int r0 = (l >> 4) * 4;
    #pragma unroll
    for (int mt = 0; mt < 4; mt++) {
        int mtg = wave*4 + mt;
        #pragma unroll
        for (int nt = 0; nt < 4; nt++) {
            int o = nt*16 + (l & 15);
            size_t idx = ((size_t)b*CH + o)*HW + (size_t)(Y + mtg)*512 + X + r0;
            float4 sv = *reinterpret_cast<const float4*>(s1 + idx);
            float4 ov;
            ov.x = acc[mt][nt][0] + sv.x;
            ov.y = acc[mt][nt][1] + sv.y;
            ov.z = acc[mt][nt][2] + sv.z;
            ov.w = acc[mt][nt][3] + sv.w;
            *reinterpret_cast<float4*>(out + idx) = ov;
        }
    }
}

extern "C" void kernel_launch(void* const* d_in, const int* in_sizes, int n_in,
                              void* d_out, int out_size, void* d_ws, size_t ws_size,
                              hipStream_t stream) {
    const float* x     = (const float*)d_in[0];
    const float* pa_w  = (const float*)d_in[1];
    const float* pa_b  = (const float*)d_in[2];
    const float* bn1_g = (const float*)d_in[3];
    const float* bn1_b = (const float*)d_in[4];
    const float* bn1_m = (const float*)d_in[5];
    const float* bn1_v = (const float*)d_in[6];
    const float* q_w   = (const float*)d_in[7];
    const float* q_b   = (const float*)d_in[8];
    const float* k_w   = (const float*)d_in[9];
    const float* k_b   = (const float*)d_in[10];
    const float* v_w   = (const float*)d_in[11];
    const float* v_b   = (const float*)d_in[12];
    const float* hp_w  = (const float*)d_in[13];
    const float* hp_b  = (const float*)d_in[14];
    const float* bn2_g = (const float*)d_in[15];
    const float* bn2_b = (const float*)d_in[16];
    const float* bn2_m = (const float*)d_in[17];
    const float* bn2_v = (const float*)d_in[18];
    const float* fc1_w = (const float*)d_in[19];
    const float* fc1_b = (const float*)d_in[20];
    const float* dw_w  = (const float*)d_in[21];
    const float* dw_b  = (const float*)d_in[22];
    const float* bn3_g = (const float*)d_in[23];
    const float* bn3_b = (const float*)d_in[24];
    const float* bn3_m = (const float*)d_in[25];
    const float* bn3_v = (const float*)d_in[26];
    const float* fc2_w = (const float*)d_in[27];
    const float* fc2_b = (const float*)d_in[28];

    float*    s1  = (float*)d_ws;                                   // 134,217,728 B
    uint32_t* h32 = (uint32_t*)((char*)d_ws + 134217728);           // 268,435,456 B
    float*    wsw = (float*)((char*)d_ws + 134217728 + 268435456);  // ~105 KB

    k0_fold<<<dim3(1), dim3(256), 0, stream>>>(
        q_w, q_b, k_w, k_b, v_w, v_b,
        bn1_g, bn1_b, bn1_m, bn1_v,
        fc1_w, fc1_b, bn2_g, bn2_b, bn2_m, bn2_v,
        fc2_w, fc2_b, hp_w, dw_w, dw_b, bn3_g, bn3_b, bn3_m, bn3_v, wsw);

    k2_attn<<<dim3(8192), dim3(256), 0, stream>>>(
        x, pa_w, pa_b, hp_b, wsw, s1);

    k3_fc1<<<dim3(4096), dim3(256), 0, stream>>>(s1, wsw, h32);

    k4_mlp2<<<dim3(1024, 2), dim3(256), 0, stream>>>(
        h32, wsw, s1, (float*)d_out);
}

// Round 5
// 658.542 us; speedup vs baseline: 2.7070x; 1.5192x over previous
//
#include <hip/hip_runtime.h>
#include <stdint.h>

#define HH 512
#define WW 512
#define HW 262144
#define CH 64
#define HID 256

typedef __attribute__((ext_vector_type(8))) short short8;
typedef __attribute__((ext_vector_type(4))) float f32x4;

// ws float-offset layout (after s1 + h byte regions):
#define WS_QKVB 0      // 128 f32  (folded q|k|v bias)
#define WS_F1B  128    // 256 f32
#define WS_F2B  384    // 64 f32
#define WS_DWP  448    // 3072 f32 (dw weights padded [ch][12])
#define WS_W1F  3520   // 16384 u16 (fc1 frags [nt16][k8 8][c16][j8])
#define WS_W2F  11712  // 16384 u16 (fc2 frags [nt4][k8 32][c16][j8])
#define WS_WQKV 19904  // 8192 u16 (qkv B-frags [nt8][k8 8][col16][j8])
#define WS_WHP  24000  // 4096 u16 (hp  A-frags [mt4][k8 8][row16][j8])

__device__ __forceinline__ float bf2f(uint16_t u) {
    return __uint_as_float(((uint32_t)u) << 16);
}
__device__ __forceinline__ uint16_t f2bf(float f) {
    uint32_t x = __float_as_uint(f);
    uint32_t r = x + 0x7fffu + ((x >> 16) & 1u);
    return (uint16_t)(r >> 16);
}

// tanh-form GELU: max |err| vs exact-erf ~3e-4 (well under bf16 rounding here)
__device__ __forceinline__ float gelu_f(float v) {
    float v2 = v * v;
    float m  = v * (-1.5957691216f - 0.0713548162726f * v2); // -2*0.79788456*(v+0.044715v^3)
    float e  = __expf(m);
    return v * __builtin_amdgcn_rcpf(1.f + e);
}

__global__ __launch_bounds__(256) void k0_fold(
    const float* __restrict__ q_w, const float* __restrict__ q_b,
    const float* __restrict__ k_w, const float* __restrict__ k_b,
    const float* __restrict__ v_w, const float* __restrict__ v_b,
    const float* __restrict__ bn1_g, const float* __restrict__ bn1_b,
    const float* __restrict__ bn1_m, const float* __restrict__ bn1_v,
    const float* __restrict__ fc1_w, const float* __restrict__ fc1_b,
    const float* __restrict__ bn2_g, const float* __restrict__ bn2_b,
    const float* __restrict__ bn2_m, const float* __restrict__ bn2_v,
    const float* __restrict__ fc2_w, const float* __restrict__ fc2_b,
    const float* __restrict__ hp_w,
    const float* __restrict__ dw_w, const float* __restrict__ dw_b,
    const float* __restrict__ bn3_g, const float* __restrict__ bn3_b,
    const float* __restrict__ bn3_m, const float* __restrict__ bn3_v,
    float* __restrict__ wsw)
{
    __shared__ float s1s[64], t1s[64], s2s[64], t2s[64], s3s[256], t3s[256];
    int tid = threadIdx.x;
    if (tid < 64) {
        float s = bn1_g[tid] * rsqrtf(bn1_v[tid] + 1e-5f);
        s1s[tid] = s; t1s[tid] = bn1_b[tid] - bn1_m[tid] * s;
        float s2 = bn2_g[tid] * rsqrtf(bn2_v[tid] + 1e-5f);
        s2s[tid] = s2; t2s[tid] = bn2_b[tid] - bn2_m[tid] * s2;
    }
    if (tid < 256) {
        float s = bn3_g[tid] * rsqrtf(bn3_v[tid] + 1e-5f);
        s3s[tid] = s;
        t3s[tid] = (dw_b[tid] - bn3_m[tid]) * s + bn3_b[tid];
    }
    __syncthreads();

    float* qkvb = wsw + WS_QKVB;
    float* f1b  = wsw + WS_F1B;
    float* f2b  = wsw + WS_F2B;
    float* dwp  = wsw + WS_DWP;
    uint16_t* w1f   = (uint16_t*)(wsw + WS_W1F);
    uint16_t* w2f   = (uint16_t*)(wsw + WS_W2F);
    uint16_t* wqkvf = (uint16_t*)(wsw + WS_WQKV);
    uint16_t* whpf  = (uint16_t*)(wsw + WS_WHP);

    if (tid < 128) {
        int o = tid;
        float a;
        if (o < 32) {
            a = q_b[o];
            for (int c = 0; c < 64; c++) a += q_w[o*64+c]*t1s[c];
        } else if (o < 64) {
            a = k_b[o-32];
            for (int c = 0; c < 64; c++) a += k_w[(o-32)*64+c]*t1s[c];
        } else {
            a = v_b[o-64];
            for (int c = 0; c < 64; c++) a += v_w[(o-64)*64+c]*t1s[c];
        }
        qkvb[o] = a;
    }
    if (tid < 256) {
        float a = fc1_b[tid];
        for (int c = 0; c < 64; c++) a += fc1_w[tid*64+c]*t2s[c];
        f1b[tid] = a;
    }
    if (tid < 64) {
        float a = fc2_b[tid];
        for (int c = 0; c < 256; c++) a += fc2_w[tid*256+c]*t3s[c];
        f2b[tid] = a;
    }
    for (int i = tid; i < 8192; i += 256) {
        int nt = i >> 10, rem = i & 1023;
        int k8 = rem >> 7, col = (rem >> 3) & 15, j = rem & 7;
        int o = nt*16 + col, c = k8*8 + j;
        float w;
        if (o < 32)      w = q_w[o*64 + c];
        else if (o < 64) w = k_w[(o-32)*64 + c];
        else             w = v_w[(o-64)*64 + c];
        wqkvf[i] = f2bf(w * s1s[c]);
    }
    for (int i = tid; i < 4096; i += 256) {
        int mt = i >> 10, rem = i & 1023;
        int k8 = rem >> 7, row = (rem >> 3) & 15, j = rem & 7;
        int o = mt*16 + row, c = k8*8 + j;
        whpf[i] = f2bf(hp_w[o*64 + c]);
    }
    for (int i = tid; i < 16384; i += 256) {
        int nt = i >> 10, rem = i & 1023;
        int k8 = rem >> 7, col = (rem >> 3) & 15, j = rem & 7;
        int c = k8*8 + j, o = nt*16 + col;
        w1f[i] = f2bf(fc1_w[o*64 + c] * s2s[c]);
    }
    for (int i = tid; i < 16384; i += 256) {
        int nt = i >> 12, rem = i & 4095;
        int k8 = rem >> 7, col = (rem >> 3) & 15, j = rem & 7;
        int c = k8*8 + j, o = nt*16 + col;
        w2f[i] = f2bf(fc2_w[o*256 + c] * s3s[c]);
    }
    for (int i = tid; i < 3072; i += 256) {
        int ch = i / 12, j = i - (i/12)*12;
        dwp[i] = (j < 9) ? dw_w[ch*9 + j] : 0.f;
    }
}

// Fused: gate(x) -> qkv (MFMA) -> window attention -> hp (MFMA) + shortcut -> s1
__global__ __launch_bounds__(256, 3) void k2_attn(
    const float* __restrict__ x,
    const float* __restrict__ pa_w, const float* __restrict__ pa_b,
    const float* __restrict__ hp_b,
    const float* __restrict__ wsw, float* __restrict__ s1out)
{
    __shared__ __align__(16) float qkvl[8832];
    __shared__ __align__(16) uint16_t gfrag[4096];
    __shared__ __align__(16) uint16_t afrag[4096];
    float* xs  = qkvl;            // [64][103]
    float* paw = qkvl + 6592;
    float* pab = qkvl + 7168;

    int tid = threadIdx.x;
    int wave = tid >> 6, l = tid & 63;
    int wid = blockIdx.x;
    int b = wid >> 12;
    int r = wid & 4095;
    int wy = r >> 6, wx = r & 63;
    int y0 = wy*8 - 1, x0 = wx*8 - 1;
    const float* xb = x + (size_t)b * CH * HW;

    for (int i = tid; i < 6400; i += 256) {
        int c = i / 100, p = i - c*100;
        int py = p / 10, px = p - py*10;
        int yy = y0 + py, xx = x0 + px;
        float v = 0.f;
        if (yy >= 0 && yy < HH && xx >= 0 && xx < WW)
            v = xb[(size_t)c*HW + yy*WW + xx];
        xs[c*103 + p] = v;
    }
    for (int i = tid; i < 576; i += 256) paw[i] = pa_w[i];
    if (tid < 64) pab[tid] = pa_b[tid];
    __syncthreads();

    for (int i = tid; i < 4096; i += 256) {
        int c = i & 63, n = i >> 6;
        int yy = n >> 3, xx = n & 7;
        const float* xc = xs + c*103;
        float conv = pab[c];
        #pragma unroll
        for (int dy = 0; dy < 3; dy++)
            #pragma unroll
            for (int dx = 0; dx < 3; dx++)
                conv += xc[(yy+dy)*10 + xx+dx] * paw[c*9 + dy*3 + dx];
        float xv = xc[(yy+1)*10 + xx+1];
        float gv = xv / (1.f + expf(-conv));
        gfrag[(n>>4)*1024 + (c>>3)*128 + (n&15)*8 + (c&7)] = f2bf(gv);
    }
    __syncthreads();

    {
        const uint16_t* wqkv = (const uint16_t*)(wsw + WS_WQKV);
        const float* qkvb = wsw + WS_QKVB;
        f32x4 acc[4][2];
        #pragma unroll
        for (int ntw = 0; ntw < 2; ntw++) {
            float bias = qkvb[(wave*2+ntw)*16 + (l & 15)];
            #pragma unroll
            for (int mt = 0; mt < 4; mt++) acc[mt][ntw] = {bias, bias, bias, bias};
        }
        #pragma unroll
        for (int kb = 0; kb < 2; kb++) {
            short8 a[4];
            #pragma unroll
            for (int mt = 0; mt < 4; mt++)
                a[mt] = *reinterpret_cast<const short8*>(&gfrag[mt*1024 + kb*512 + 8*l]);
            #pragma unroll
            for (int ntw = 0; ntw < 2; ntw++) {
                int nt = wave*2 + ntw;
                short8 bf = *reinterpret_cast<const short8*>(&wqkv[nt*1024 + kb*512 + 8*l]);
                #pragma unroll
                for (int mt = 0; mt < 4; mt++)
                    acc[mt][ntw] = __builtin_amdgcn_mfma_f32_16x16x32_bf16(a[mt], bf, acc[mt][ntw], 0, 0, 0);
            }
        }
        __syncthreads();
        #pragma unroll
        for (int ntw = 0; ntw < 2; ntw++) {
            int o = (wave*2+ntw)*16 + (l & 15);
            #pragma unroll
            for (int mt = 0; mt < 4; mt++) {
                int px0 = mt*16 + (l >> 4)*4;
                #pragma unroll
                for (int rr = 0; rr < 4; rr++)
                    qkvl[o*69 + px0 + rr] = acc[mt][ntw][rr];
            }
        }
    }
    __syncthreads();

    {
        int hd = tid >> 4, l16 = tid & 15;
        float a0[4], a1[4], a2[4], a3[4], a4[4], a5[4], a6[4], a7[4];
        #pragma unroll
        for (int j = 0; j < 4; j++) {
            int px = l16 + 16*j;
            a0[j] = qkvl[(2*hd    )*69 + px];
            a1[j] = qkvl[(2*hd + 1)*69 + px];
            a2[j] = qkvl[(32 + 2*hd    )*69 + px];
            a3[j] = qkvl[(32 + 2*hd + 1)*69 + px];
            a4[j] = qkvl[(64 + 4*hd    )*69 + px];
            a5[j] = qkvl[(64 + 4*hd + 1)*69 + px];
            a6[j] = qkvl[(64 + 4*hd + 2)*69 + px];
            a7[j] = qkvl[(64 + 4*hd + 3)*69 + px];
        }
        #pragma unroll
        for (int j = 0; j < 4; j++) {
            float m = fmaxf(a0[j], a1[j]);
            float e0 = expf(a0[j]-m), e1 = expf(a1[j]-m);
            float inv = 1.f/(e0+e1);
            a0[j] = e0*inv; a1[j] = e1*inv;
        }
        float m0 = fmaxf(fmaxf(a2[0],a2[1]), fmaxf(a2[2],a2[3]));
        float m1 = fmaxf(fmaxf(a3[0],a3[1]), fmaxf(a3[2],a3[3]));
        #pragma unroll
        for (int s = 1; s < 16; s <<= 1) {
            m0 = fmaxf(m0, __shfl_xor(m0, s, 64));
            m1 = fmaxf(m1, __shfl_xor(m1, s, 64));
        }
        float sum0 = 0.f, sum1 = 0.f;
        #pragma unroll
        for (int j = 0; j < 4; j++) {
            a2[j] = expf(a2[j]-m0); a3[j] = expf(a3[j]-m1);
            sum0 += a2[j]; sum1 += a3[j];
        }
        #pragma unroll
        for (int s = 1; s < 16; s <<= 1) {
            sum0 += __shfl_xor(sum0, s, 64);
            sum1 += __shfl_xor(sum1, s, 64);
        }
        float iv0 = 1.f/sum0, iv1 = 1.f/sum1;
        #pragma unroll
        for (int j = 0; j < 4; j++) { a2[j] *= iv0; a3[j] *= iv1; }
        float ctx0[4], ctx1[4];
        #pragma unroll
        for (int e = 0; e < 4; e++) {
            float ve0, ve1, ve2, ve3;
            if (e==0) { ve0=a4[0]; ve1=a4[1]; ve2=a4[2]; ve3=a4[3]; }
            else if (e==1) { ve0=a5[0]; ve1=a5[1]; ve2=a5[2]; ve3=a5[3]; }
            else if (e==2) { ve0=a6[0]; ve1=a6[1]; ve2=a6[2]; ve3=a6[3]; }
            else { ve0=a7[0]; ve1=a7[1]; ve2=a7[2]; ve3=a7[3]; }
            float c0 = a2[0]*ve0 + a2[1]*ve1 + a2[2]*ve2 + a2[3]*ve3;
            float c1 = a3[0]*ve0 + a3[1]*ve1 + a3[2]*ve2 + a3[3]*ve3;
            #pragma unroll
            for (int s = 1; s < 16; s <<= 1) {
                c0 += __shfl_xor(c0, s, 64);
                c1 += __shfl_xor(c1, s, 64);
            }
            ctx0[e] = c0; ctx1[e] = c1;
        }
        float p00=0.f, p01=0.f, p10=0.f, p11=0.f;
        #pragma unroll
        for (int j = 0; j < 4; j++) {
            p00 += a0[j]*a2[j]; p01 += a0[j]*a3[j];
            p10 += a1[j]*a2[j]; p11 += a1[j]*a3[j];
        }
        #pragma unroll
        for (int s = 1; s < 16; s <<= 1) {
            p00 += __shfl_xor(p00, s, 64); p01 += __shfl_xor(p01, s, 64);
            p10 += __shfl_xor(p10, s, 64); p11 += __shfl_xor(p11, s, 64);
        }
        const float CH_SCALE = 0.70710678118654752f;
        p00 *= CH_SCALE; p01 *= CH_SCALE; p10 *= CH_SCALE; p11 *= CH_SCALE;
        float dc = fmaxf(fmaxf(p00,p01), fmaxf(p10,p11)) + 0.25f*(p00+p01+p10+p11);

        #pragma unroll
        for (int j = 0; j < 4; j++) {
            uint16_t t[4];
            #pragma unroll
            for (int e = 0; e < 4; e++)
                t[e] = f2bf((a0[j]*ctx0[e] + a1[j]*ctx1[e]) * dc);
            *reinterpret_cast<uint64_t*>(
                &afrag[j*1024 + (hd>>1)*128 + l16*8 + (hd&1)*4]) =
                *reinterpret_cast<const uint64_t*>(t);
        }
    }
    __syncthreads();

    {
        const uint16_t* whp = (const uint16_t*)(wsw + WS_WHP);
        int nt = wave;
        f32x4 oacc[4];
        #pragma unroll
        for (int mt = 0; mt < 4; mt++) {
            int o0 = mt*16 + (l >> 4)*4;
            oacc[mt] = {hp_b[o0], hp_b[o0+1], hp_b[o0+2], hp_b[o0+3]};
        }
        #pragma unroll
        for (int kb = 0; kb < 2; kb++) {
            short8 bf = *reinterpret_cast<const short8*>(&afrag[nt*1024 + kb*512 + 8*l]);
            #pragma unroll
            for (int mt = 0; mt < 4; mt++) {
                short8 a = *reinterpret_cast<const short8*>(&whp[mt*1024 + kb*512 + 8*l]);
                oacc[mt] = __builtin_amdgcn_mfma_f32_16x16x32_bf16(a, bf, oacc[mt], 0, 0, 0);
            }
        }
        int px = nt*16 + (l & 15);
        int yy = wy*8 + (px >> 3), xx = wx*8 + (px & 7);
        size_t pbase = (size_t)b * CH * HW + (size_t)yy * WW + xx;
        #pragma unroll
        for (int mt = 0; mt < 4; mt++) {
            #pragma unroll
            for (int rr = 0; rr < 4; rr++) {
                int o = mt*16 + (l >> 4)*4 + rr;
                float g = bf2f(gfrag[(px>>4)*1024 + (o>>3)*128 + (px&15)*8 + (o&7)]);
                s1out[pbase + (size_t)o * HW] = oacc[mt][rr] + g;
            }
        }
    }
}

// Fused MLP: fc1 (MFMA) + GELU + dwconv3 (bn3 folded) + fc2 (MFMA) + residual.
// One block per 16x16 tile; halo 18x18; h never touches global memory.
__global__ __launch_bounds__(256, 2) void k3_mlp(
    const float* __restrict__ s1, const float* __restrict__ wsw,
    float* __restrict__ out)
{
    // s1-halo bf16 fragments: [21 pt][2 kb][(k8,row,j) 512] ; px = hy*18+hx, pad to 336
    __shared__ __align__(16) uint16_t sfrag[21504];   // 43008 B
    // h chunk (32 ch/pass): [18 hy][20 hx][40 ch-pad]  (px stride 80B = 5 slots)
    __shared__ __align__(16) uint16_t hbuf[14400];    // 28800 B

    const float* f1b = wsw + WS_F1B;
    const float* f2b = wsw + WS_F2B;
    const float* dwp = wsw + WS_DWP;
    const uint16_t* w1f = (const uint16_t*)(wsw + WS_W1F);
    const uint16_t* w2f = (const uint16_t*)(wsw + WS_W2F);

    int tid = threadIdx.x;
    int wave = tid >> 6, l = tid & 63;
    int X = blockIdx.x * 16, Y = blockIdx.y * 16;
    int b = blockIdx.z;

    // ---- phase 0: s1 halo -> sfrag (coalesced 96B row-segments) ----
    const float* sb = s1 + (size_t)b * CH * HW;
    for (int i = tid; i < 6912; i += 256) {
        int xseg = i % 6;
        int rem = i / 6;
        int hy = rem % 18;
        int c  = rem / 18;
        int yy = Y - 1 + hy;
        int x0 = X - 4 + xseg * 4;
        float4 v = {0.f, 0.f, 0.f, 0.f};
        if ((unsigned)yy < 512u) {
            if (x0 >= 0 && x0 <= 508) {
                v = *reinterpret_cast<const float4*>(&sb[(size_t)c*HW + yy*512 + x0]);
            } else {
                const float* rp = &sb[(size_t)c*HW + yy*512];
                float tv[4];
                #pragma unroll
                for (int e = 0; e < 4; e++) {
                    int xx = x0 + e;
                    tv[e] = ((unsigned)xx < 512u) ? rp[xx] : 0.f;
                }
                v = {tv[0], tv[1], tv[2], tv[3]};
            }
        }
        float vv[4] = {v.x, v.y, v.z, v.w};
        #pragma unroll
        for (int e = 0; e < 4; e++) {
            int hx = x0 + e - (X - 1);
            if ((unsigned)hx < 18u) {
                int px = hy*18 + hx;
                sfrag[(px>>4)*1024 + (c>>3)*128 + (px&15)*8 + (c&7)] = f2bf(vv[e]);
            }
        }
    }

    // fc2 accumulators persist across all passes: D col = out-ch, rows = 4 x-positions
    f32x4 acc[4][4];
    #pragma unroll
    for (int nt = 0; nt < 4; nt++) {
        float bias = f2b[nt*16 + (l & 15)];
        #pragma unroll
        for (int mi = 0; mi < 4; mi++) acc[mi][nt] = {bias, bias, bias, bias};
    }
    __syncthreads();

    for (int cc = 0; cc < 8; cc++) {
        // ---- fc1 for hidden ch [cc*32, cc*32+32): A = weights, B = pixels ----
        short8 wA[2][2];
        #pragma unroll
        for (int mtw = 0; mtw < 2; mtw++)
            #pragma unroll
            for (int kb = 0; kb < 2; kb++)
                wA[mtw][kb] = *reinterpret_cast<const short8*>(
                    &w1f[(cc*2 + mtw)*1024 + kb*512 + 8*l]);
        float4 hb0 = *reinterpret_cast<const float4*>(&f1b[cc*32      + (l>>4)*4]);
        float4 hb1 = *reinterpret_cast<const float4*>(&f1b[cc*32 + 16 + (l>>4)*4]);

        for (int pt = wave; pt < 21; pt += 4) {
            f32x4 h0 = {hb0.x, hb0.y, hb0.z, hb0.w};
            f32x4 h1 = {hb1.x, hb1.y, hb1.z, hb1.w};
            #pragma unroll
            for (int kb = 0; kb < 2; kb++) {
                short8 bf = *reinterpret_cast<const short8*>(&sfrag[pt*1024 + kb*512 + 8*l]);
                h0 = __builtin_amdgcn_mfma_f32_16x16x32_bf16(wA[0][kb], bf, h0, 0, 0, 0);
                h1 = __builtin_amdgcn_mfma_f32_16x16x32_bf16(wA[1][kb], bf, h1, 0, 0, 0);
            }
            int px = pt*16 + (l & 15);
            if (px < 324) {
                int hy = px / 18, hx = px - hy*18;
                bool img = ((unsigned)(Y-1+hy) < 512u) && ((unsigned)(X-1+hx) < 512u);
                uint64_t v0 = 0, v1 = 0;
                if (img) {
                    uint16_t t0[4], t1[4];
                    #pragma unroll
                    for (int rr = 0; rr < 4; rr++) {
                        t0[rr] = f2bf(gelu_f(h0[rr]));
                        t1[rr] = f2bf(gelu_f(h1[rr]));
                    }
                    v0 = *reinterpret_cast<const uint64_t*>(t0);
                    v1 = *reinterpret_cast<const uint64_t*>(t1);
                }
                int base = (hy*20 + hx)*40 + (l>>4)*4;
                *reinterpret_cast<uint64_t*>(&hbuf[base])      = v0;
                *reinterpret_cast<uint64_t*>(&hbuf[base + 16]) = v1;
            }
        }
        __syncthreads();

        // ---- dwconv (row-register rotation) + fc2 MFMA accumulate ----
        float dw[8][9];
        {
            int chg = cc*32 + (l>>4)*8;
            #pragma unroll
            for (int c8 = 0; c8 < 8; c8++) {
                const float* wp = dwp + (chg + c8) * 12;
                float4 w0 = *reinterpret_cast<const float4*>(wp);
                float4 w1 = *reinterpret_cast<const float4*>(wp + 4);
                float4 w2 = *reinterpret_cast<const float4*>(wp + 8);
                dw[c8][0]=w0.x; dw[c8][1]=w0.y; dw[c8][2]=w0.z; dw[c8][3]=w0.w;
                dw[c8][4]=w1.x; dw[c8][5]=w1.y; dw[c8][6]=w1.z; dw[c8][7]=w1.w;
                dw[c8][8]=w2.x;
            }
        }
        short8 bfr[4];
        #pragma unroll
        for (int nt = 0; nt < 4; nt++)
            bfr[nt] = *reinterpret_cast<const short8*>(&w2f[nt*4096 + cc*512 + 8*l]);

        uint4 R[3][3];
        int rbase = ((wave*4)*20 + (l & 15))*40 + (l>>4)*8;
        #pragma unroll
        for (int pre = 0; pre < 2; pre++) {
            #pragma unroll
            for (int dx = 0; dx < 3; dx++)
                R[pre][dx] = *reinterpret_cast<const uint4*>(&hbuf[rbase + pre*800 + dx*40]);
        }
        #pragma unroll
        for (int mi = 0; mi < 4; mi++) {
            #pragma unroll
            for (int dx = 0; dx < 3; dx++)
                R[(mi+2)%3][dx] = *reinterpret_cast<const uint4*>(
                    &hbuf[rbase + (mi+2)*800 + dx*40]);
            float t0=0.f,t1=0.f,t2=0.f,t3=0.f,t4=0.f,t5=0.f,t6=0.f,t7=0.f;
            #pragma unroll
            for (int dy = 0; dy < 3; dy++) {
                #pragma unroll
                for (int dx = 0; dx < 3; dx++) {
                    uint4 q = R[(mi+dy)%3][dx];
                    int wi = dy*3 + dx;
                    t0 += __uint_as_float(q.x << 16)         * dw[0][wi];
                    t1 += __uint_as_float(q.x & 0xffff0000u) * dw[1][wi];
                    t2 += __uint_as_float(q.y << 16)         * dw[2][wi];
                    t3 += __uint_as_float(q.y & 0xffff0000u) * dw[3][wi];
                    t4 += __uint_as_float(q.z << 16)         * dw[4][wi];
                    t5 += __uint_as_float(q.z & 0xffff0000u) * dw[5][wi];
                    t6 += __uint_as_float(q.w << 16)         * dw[6][wi];
                    t7 += __uint_as_float(q.w & 0xffff0000u) * dw[7][wi];
                }
            }
            short8 af;
            af[0]=(short)f2bf(t0); af[1]=(short)f2bf(t1);
            af[2]=(short)f2bf(t2); af[3]=(short)f2bf(t3);
            af[4]=(short)f2bf(t4); af[5]=(short)f2bf(t5);
            af[6]=(short)f2bf(t6); af[7]=(short)f2bf(t7);
            #pragma unroll
            for (int nt = 0; nt < 4; nt++)
                acc[mi][nt] = __builtin_amdgcn_mfma_f32_16x16x32_bf16(af, bfr[nt], acc[mi][nt], 0, 0, 0);
        }
        __syncthreads();
    }

    // ---- epilogue: + residual s1 -> out ----
    int r0 = (l >> 4) * 4;
    #pragma unroll
    for (int mi = 0; mi < 4; mi++) {
        int yrow = Y + wave*4 + mi;
        #pragma unroll
        for (int nt = 0; nt < 4; nt++) {
            int o = nt*16 + (l & 15);
            size_t idx = ((size_t)b*CH + o)*HW + (size_t)yrow*512 + X + r0;
            float4 sv = *reinterpret_cast<const float4*>(s1 + idx);
            float4 ov;
            ov.x = acc[mi][nt][0] + sv.x;
            ov.y = acc[mi][nt][1] + sv.y;
            ov.z = acc[mi][nt][2] + sv.z;
            ov.w = acc[mi][nt][3] + sv.w;
            *reinterpret_cast<float4*>(out + idx) = ov;
        }
    }
}

extern "C" void kernel_launch(void* const* d_in, const int* in_sizes, int n_in,
                              void* d_out, int out_size, void* d_ws, size_t ws_size,
                              hipStream_t stream) {
    const float* x     = (const float*)d_in[0];
    const float* pa_w  = (const float*)d_in[1];
    const float* pa_b  = (const float*)d_in[2];
    const float* bn1_g = (const float*)d_in[3];
    const float* bn1_b = (const float*)d_in[4];
    const float* bn1_m = (const float*)d_in[5];
    const float* bn1_v = (const float*)d_in[6];
    const float* q_w   = (const float*)d_in[7];
    const float* q_b   = (const float*)d_in[8];
    const float* k_w   = (const float*)d_in[9];
    const float* k_b   = (const float*)d_in[10];
    const float* v_w   = (const float*)d_in[11];
    const float* v_b   = (const float*)d_in[12];
    const float* hp_w  = (const float*)d_in[13];
    const float* hp_b  = (const float*)d_in[14];
    const float* bn2_g = (const float*)d_in[15];
    const float* bn2_b = (const float*)d_in[16];
    const float* bn2_m = (const float*)d_in[17];
    const float* bn2_v = (const float*)d_in[18];
    const float* fc1_w = (const float*)d_in[19];
    const float* fc1_b = (const float*)d_in[20];
    const float* dw_w  = (const float*)d_in[21];
    const float* dw_b  = (const float*)d_in[22];
    const float* bn3_g = (const float*)d_in[23];
    const float* bn3_b = (const float*)d_in[24];
    const float* bn3_m = (const float*)d_in[25];
    const float* bn3_v = (const float*)d_in[26];
    const float* fc2_w = (const float*)d_in[27];
    const float* fc2_b = (const float*)d_in[28];

    float* s1  = (float*)d_ws;                                   // 134,217,728 B
    float* wsw = (float*)((char*)d_ws + 134217728 + 268435456);  // ~105 KB

    k0_fold<<<dim3(1), dim3(256), 0, stream>>>(
        q_w, q_b, k_w, k_b, v_w, v_b,
        bn1_g, bn1_b, bn1_m, bn1_v,
        fc1_w, fc1_b, bn2_g, bn2_b, bn2_m, bn2_v,
        fc2_w, fc2_b, hp_w, dw_w, dw_b, bn3_g, bn3_b, bn3_m, bn3_v, wsw);

    k2_attn<<<dim3(8192), dim3(256), 0, stream>>>(
        x, pa_w, pa_b, hp_b, wsw, s1);

    k3_mlp<<<dim3(32, 32, 2), dim3(256), 0, stream>>>(
        s1, wsw, (float*)d_out);
}

// Round 6
// 434.033 us; speedup vs baseline: 4.1073x; 1.5173x over previous
//
#include <hip/hip_runtime.h>
#include <stdint.h>

#define HH 512
#define WW 512
#define HW 262144
#define CH 64
#define HID 256

typedef __attribute__((ext_vector_type(8))) short short8;
typedef __attribute__((ext_vector_type(4))) float f32x4;

// ws float-offset layout (wsw region):
#define WS_QKVB 0      // 128 f32  (folded q|k|v bias)
#define WS_F1B  128    // 256 f32
#define WS_F2B  384    // 64 f32
#define WS_DWP  448    // 3072 f32 (dw weights [tap9][ch256])
#define WS_W1F  3520   // 16384 u16 (fc1 frags [nt16][k8 8][c16][j8])
#define WS_W2F  11712  // 16384 u16 (fc2 frags [nt4][k8 32][c16][j8])
#define WS_WQKV 19904  // 8192 u16 (qkv B-frags [nt8][k8 8][col16][j8])
#define WS_WHP  24000  // 4096 u16 (hp  A-frags [mt4][k8 8][row16][j8])

__device__ __forceinline__ float bf2f(uint16_t u) {
    return __uint_as_float(((uint32_t)u) << 16);
}
__device__ __forceinline__ uint16_t f2bf(float f) {
    uint32_t x = __float_as_uint(f);
    uint32_t r = x + 0x7fffu + ((x >> 16) & 1u);
    return (uint16_t)(r >> 16);
}
__device__ __forceinline__ float h2f(uint16_t u) {
    _Float16 h;
    __builtin_memcpy(&h, &u, 2);
    return (float)h;
}
__device__ __forceinline__ uint16_t f2h(float f) {
    _Float16 h = (_Float16)f;
    uint16_t u;
    __builtin_memcpy(&u, &h, 2);
    return u;
}

// tanh-form GELU
__device__ __forceinline__ float gelu_f(float v) {
    float v2 = v * v;
    float m  = v * (-1.5957691216f - 0.0713548162726f * v2);
    float e  = __expf(m);
    return v * __builtin_amdgcn_rcpf(1.f + e);
}

__global__ __launch_bounds__(256) void k0_fold(
    const float* __restrict__ q_w, const float* __restrict__ q_b,
    const float* __restrict__ k_w, const float* __restrict__ k_b,
    const float* __restrict__ v_w, const float* __restrict__ v_b,
    const float* __restrict__ bn1_g, const float* __restrict__ bn1_b,
    const float* __restrict__ bn1_m, const float* __restrict__ bn1_v,
    const float* __restrict__ fc1_w, const float* __restrict__ fc1_b,
    const float* __restrict__ bn2_g, const float* __restrict__ bn2_b,
    const float* __restrict__ bn2_m, const float* __restrict__ bn2_v,
    const float* __restrict__ fc2_w, const float* __restrict__ fc2_b,
    const float* __restrict__ hp_w,
    const float* __restrict__ dw_w, const float* __restrict__ dw_b,
    const float* __restrict__ bn3_g, const float* __restrict__ bn3_b,
    const float* __restrict__ bn3_m, const float* __restrict__ bn3_v,
    float* __restrict__ wsw)
{
    __shared__ float s1s[64], t1s[64], s2s[64], t2s[64], s3s[256], t3s[256];
    int tid = threadIdx.x;
    if (tid < 64) {
        float s = bn1_g[tid] * rsqrtf(bn1_v[tid] + 1e-5f);
        s1s[tid] = s; t1s[tid] = bn1_b[tid] - bn1_m[tid] * s;
        float s2 = bn2_g[tid] * rsqrtf(bn2_v[tid] + 1e-5f);
        s2s[tid] = s2; t2s[tid] = bn2_b[tid] - bn2_m[tid] * s2;
    }
    if (tid < 256) {
        float s = bn3_g[tid] * rsqrtf(bn3_v[tid] + 1e-5f);
        s3s[tid] = s;
        t3s[tid] = (dw_b[tid] - bn3_m[tid]) * s + bn3_b[tid];
    }
    __syncthreads();

    float* qkvb = wsw + WS_QKVB;
    float* f1b  = wsw + WS_F1B;
    float* f2b  = wsw + WS_F2B;
    float* dwp  = wsw + WS_DWP;
    uint16_t* w1f   = (uint16_t*)(wsw + WS_W1F);
    uint16_t* w2f   = (uint16_t*)(wsw + WS_W2F);
    uint16_t* wqkvf = (uint16_t*)(wsw + WS_WQKV);
    uint16_t* whpf  = (uint16_t*)(wsw + WS_WHP);

    if (tid < 128) {
        int o = tid;
        float a;
        if (o < 32) {
            a = q_b[o];
            for (int c = 0; c < 64; c++) a += q_w[o*64+c]*t1s[c];
        } else if (o < 64) {
            a = k_b[o-32];
            for (int c = 0; c < 64; c++) a += k_w[(o-32)*64+c]*t1s[c];
        } else {
            a = v_b[o-64];
            for (int c = 0; c < 64; c++) a += v_w[(o-64)*64+c]*t1s[c];
        }
        qkvb[o] = a;
    }
    if (tid < 256) {
        float a = fc1_b[tid];
        for (int c = 0; c < 64; c++) a += fc1_w[tid*64+c]*t2s[c];
        f1b[tid] = a;
    }
    if (tid < 64) {
        float a = fc2_b[tid];
        for (int c = 0; c < 256; c++) a += fc2_w[tid*256+c]*t3s[c];
        f2b[tid] = a;
    }
    for (int i = tid; i < 8192; i += 256) {
        int nt = i >> 10, rem = i & 1023;
        int k8 = rem >> 7, col = (rem >> 3) & 15, j = rem & 7;
        int o = nt*16 + col, c = k8*8 + j;
        float w;
        if (o < 32)      w = q_w[o*64 + c];
        else if (o < 64) w = k_w[(o-32)*64 + c];
        else             w = v_w[(o-64)*64 + c];
        wqkvf[i] = f2bf(w * s1s[c]);
    }
    for (int i = tid; i < 4096; i += 256) {
        int mt = i >> 10, rem = i & 1023;
        int k8 = rem >> 7, row = (rem >> 3) & 15, j = rem & 7;
        int o = mt*16 + row, c = k8*8 + j;
        whpf[i] = f2bf(hp_w[o*64 + c]);
    }
    for (int i = tid; i < 16384; i += 256) {
        int nt = i >> 10, rem = i & 1023;
        int k8 = rem >> 7, col = (rem >> 3) & 15, j = rem & 7;
        int c = k8*8 + j, o = nt*16 + col;
        w1f[i] = f2bf(fc1_w[o*64 + c] * s2s[c]);
    }
    for (int i = tid; i < 16384; i += 256) {
        int nt = i >> 12, rem = i & 4095;
        int k8 = rem >> 7, col = (rem >> 3) & 15, j = rem & 7;
        int c = k8*8 + j, o = nt*16 + col;
        w2f[i] = f2bf(fc2_w[o*256 + c] * s3s[c]);
    }
    // dw weights re-laid [tap][ch]
    for (int i = tid; i < 2304; i += 256) {
        int t = i >> 8, ch = i & 255;
        dwp[i] = dw_w[ch*9 + t];
    }
}

// Fused: gate(x) -> qkv (MFMA, f16 LDS) -> window attention -> hp (MFMA) + shortcut
// -> s1 (bf16 NHWC). LDS 36KB -> 4 blocks/CU.
__global__ __launch_bounds__(256, 4) void k2_attn(
    const float* __restrict__ x,
    const float* __restrict__ pa_w, const float* __restrict__ pa_b,
    const float* __restrict__ hp_b,
    const float* __restrict__ wsw, uint16_t* __restrict__ s1out)
{
    // regionA: phase 1-2 = bf16 halo [64][10][16]; phase 3+ = qkv f16 [128][68]
    __shared__ __align__(16) uint16_t regionA[10240];
    __shared__ __align__(16) uint16_t gfrag[4096];   // gated-x bf16 frags
    __shared__ __align__(16) uint16_t afrag[4096];   // att bf16 B-frags
    uint16_t* xs  = regionA;
    uint16_t* qkv = regionA;

    int tid = threadIdx.x;
    int wave = tid >> 6, l = tid & 63;
    int wid = blockIdx.x;
    int b = wid >> 12;
    int r = wid & 4095;
    int wy = r >> 6, wx = r & 63;
    int y0 = wy*8 - 1;
    int x0g = wx*8 - 4;
    const float* xb = x + (size_t)b * CH * HW;

    // ---- phase 1: halo load (640 rows of 16 f32 -> bf16) ----
    #pragma unroll
    for (int k = 0; k < 3; k++) {
        int rr = k*256 + tid;
        if (rr < 640) {
            int c = rr / 10;
            int py = rr - c*10;
            int yy = y0 + py;
            uint16_t* dst = &xs[c*160 + py*16];
            if ((unsigned)yy < 512u) {
                const float* src = &xb[(size_t)c*HW + (size_t)yy*512];
                #pragma unroll
                for (int s = 0; s < 4; s++) {
                    int gx = x0g + s*4;
                    uint16_t tv[4];
                    if (gx >= 0 && gx <= 508) {
                        float4 v = *reinterpret_cast<const float4*>(&src[gx]);
                        tv[0] = f2bf(v.x); tv[1] = f2bf(v.y);
                        tv[2] = f2bf(v.z); tv[3] = f2bf(v.w);
                    } else {
                        #pragma unroll
                        for (int e = 0; e < 4; e++) {
                            int gx2 = gx + e;
                            tv[e] = f2bf(((unsigned)gx2 < 512u) ? src[gx2] : 0.f);
                        }
                    }
                    *reinterpret_cast<uint64_t*>(&dst[s*4]) =
                        *reinterpret_cast<const uint64_t*>(tv);
                }
            } else {
                #pragma unroll
                for (int s = 0; s < 4; s++)
                    *reinterpret_cast<uint64_t*>(&dst[s*4]) = 0ull;
            }
        }
    }
    __syncthreads();

    // ---- phase 2: gate (register-tiled: thread = (c, 2-row strip)) ----
    {
        int c = tid & 63, yh = tid >> 6;   // yh 0..3 -> output rows yh*2, yh*2+1
        float pw[9];
        #pragma unroll
        for (int t = 0; t < 9; t++) pw[t] = pa_w[c*9 + t];
        float pb = pa_b[c];
        // 4 tap rows x 12 values (x_local 2..13)
        float va[4][12];
        #pragma unroll
        for (int tr = 0; tr < 4; tr++) {
            const uint16_t* rp = &xs[c*160 + (yh*2 + tr)*16];
            #pragma unroll
            for (int s = 0; s < 6; s++) {
                uint32_t u = *reinterpret_cast<const uint32_t*>(&rp[2 + s*2]);
                va[tr][s*2]   = __uint_as_float(u << 16);
                va[tr][s*2+1] = __uint_as_float(u & 0xffff0000u);
            }
        }
        #pragma unroll
        for (int dy2 = 0; dy2 < 2; dy2++) {
            int y = yh*2 + dy2;
            #pragma unroll
            for (int xx = 0; xx < 8; xx++) {
                float conv = pb;
                #pragma unroll
                for (int dy = 0; dy < 3; dy++)
                    #pragma unroll
                    for (int dx = 0; dx < 3; dx++)
                        conv += va[dy2+dy][xx+1+dx] * pw[dy*3+dx];
                float xc = va[dy2+1][xx+2];
                float gv = xc / (1.f + __expf(-conv));
                int n = y*8 + xx;
                gfrag[(n>>4)*1024 + (c>>3)*128 + (n&15)*8 + (c&7)] = f2bf(gv);
            }
        }
    }
    __syncthreads();

    // ---- phase 3: qkv MFMA -> qkv f16 [128 out][68-pad px] ----
    {
        const uint16_t* wqkv = (const uint16_t*)(wsw + WS_WQKV);
        const float* qkvb = wsw + WS_QKVB;
        f32x4 acc[4][2];
        #pragma unroll
        for (int ntw = 0; ntw < 2; ntw++) {
            float bias = qkvb[(wave*2+ntw)*16 + (l & 15)];
            #pragma unroll
            for (int mt = 0; mt < 4; mt++) acc[mt][ntw] = {bias, bias, bias, bias};
        }
        #pragma unroll
        for (int kb = 0; kb < 2; kb++) {
            short8 a[4];
            #pragma unroll
            for (int mt = 0; mt < 4; mt++)
                a[mt] = *reinterpret_cast<const short8*>(&gfrag[mt*1024 + kb*512 + 8*l]);
            #pragma unroll
            for (int ntw = 0; ntw < 2; ntw++) {
                int nt = wave*2 + ntw;
                short8 bf = *reinterpret_cast<const short8*>(&wqkv[nt*1024 + kb*512 + 8*l]);
                #pragma unroll
                for (int mt = 0; mt < 4; mt++)
                    acc[mt][ntw] = __builtin_amdgcn_mfma_f32_16x16x32_bf16(a[mt], bf, acc[mt][ntw], 0, 0, 0);
            }
        }
        #pragma unroll
        for (int ntw = 0; ntw < 2; ntw++) {
            int o = (wave*2+ntw)*16 + (l & 15);
            #pragma unroll
            for (int mt = 0; mt < 4; mt++) {
                int px0 = mt*16 + (l >> 4)*4;
                uint16_t t[4];
                #pragma unroll
                for (int rr = 0; rr < 4; rr++) t[rr] = f2h(acc[mt][ntw][rr]);
                *reinterpret_cast<uint64_t*>(&qkv[o*68 + px0]) =
                    *reinterpret_cast<const uint64_t*>(t);
            }
        }
    }
    __syncthreads();

    // ---- phase 4: attention (16-lane head groups) ----
    {
        int hd = tid >> 4, l16 = tid & 15;
        float a0[4], a1[4], a2[4], a3[4], a4[4], a5[4], a6[4], a7[4];
        #pragma unroll
        for (int j = 0; j < 4; j++) {
            int px = l16 + 16*j;
            a0[j] = h2f(qkv[(2*hd    )*68 + px]);
            a1[j] = h2f(qkv[(2*hd + 1)*68 + px]);
            a2[j] = h2f(qkv[(32 + 2*hd    )*68 + px]);
            a3[j] = h2f(qkv[(32 + 2*hd + 1)*68 + px]);
            a4[j] = h2f(qkv[(64 + 4*hd    )*68 + px]);
            a5[j] = h2f(qkv[(64 + 4*hd + 1)*68 + px]);
            a6[j] = h2f(qkv[(64 + 4*hd + 2)*68 + px]);
            a7[j] = h2f(qkv[(64 + 4*hd + 3)*68 + px]);
        }
        #pragma unroll
        for (int j = 0; j < 4; j++) {
            float m = fmaxf(a0[j], a1[j]);
            float e0 = __expf(a0[j]-m), e1 = __expf(a1[j]-m);
            float inv = 1.f/(e0+e1);
            a0[j] = e0*inv; a1[j] = e1*inv;
        }
        float m0 = fmaxf(fmaxf(a2[0],a2[1]), fmaxf(a2[2],a2[3]));
        float m1 = fmaxf(fmaxf(a3[0],a3[1]), fmaxf(a3[2],a3[3]));
        #pragma unroll
        for (int s = 1; s < 16; s <<= 1) {
            m0 = fmaxf(m0, __shfl_xor(m0, s, 64));
            m1 = fmaxf(m1, __shfl_xor(m1, s, 64));
        }
        float sum0 = 0.f, sum1 = 0.f;
        #pragma unroll
        for (int j = 0; j < 4; j++) {
            a2[j] = __expf(a2[j]-m0); a3[j] = __expf(a3[j]-m1);
            sum0 += a2[j]; sum1 += a3[j];
        }
        #pragma unroll
        for (int s = 1; s < 16; s <<= 1) {
            sum0 += __shfl_xor(sum0, s, 64);
            sum1 += __shfl_xor(sum1, s, 64);
        }
        float iv0 = 1.f/sum0, iv1 = 1.f/sum1;
        #pragma unroll
        for (int j = 0; j < 4; j++) { a2[j] *= iv0; a3[j] *= iv1; }
        float ctx0[4], ctx1[4];
        #pragma unroll
        for (int e = 0; e < 4; e++) {
            float ve0, ve1, ve2, ve3;
            if (e==0) { ve0=a4[0]; ve1=a4[1]; ve2=a4[2]; ve3=a4[3]; }
            else if (e==1) { ve0=a5[0]; ve1=a5[1]; ve2=a5[2]; ve3=a5[3]; }
            else if (e==2) { ve0=a6[0]; ve1=a6[1]; ve2=a6[2]; ve3=a6[3]; }
            else { ve0=a7[0]; ve1=a7[1]; ve2=a7[2]; ve3=a7[3]; }
            float c0 = a2[0]*ve0 + a2[1]*ve1 + a2[2]*ve2 + a2[3]*ve3;
            float c1 = a3[0]*ve0 + a3[1]*ve1 + a3[2]*ve2 + a3[3]*ve3;
            #pragma unroll
            for (int s = 1; s < 16; s <<= 1) {
                c0 += __shfl_xor(c0, s, 64);
                c1 += __shfl_xor(c1, s, 64);
            }
            ctx0[e] = c0; ctx1[e] = c1;
        }
        float p00=0.f, p01=0.f, p10=0.f, p11=0.f;
        #pragma unroll
        for (int j = 0; j < 4; j++) {
            p00 += a0[j]*a2[j]; p01 += a0[j]*a3[j];
            p10 += a1[j]*a2[j]; p11 += a1[j]*a3[j];
        }
        #pragma unroll
        for (int s = 1; s < 16; s <<= 1) {
            p00 += __shfl_xor(p00, s, 64); p01 += __shfl_xor(p01, s, 64);
            p10 += __shfl_xor(p10, s, 64); p11 += __shfl_xor(p11, s, 64);
        }
        const float CH_SCALE = 0.70710678118654752f;
        p00 *= CH_SCALE; p01 *= CH_SCALE; p10 *= CH_SCALE; p11 *= CH_SCALE;
        float dc = fmaxf(fmaxf(p00,p01), fmaxf(p10,p11)) + 0.25f*(p00+p01+p10+p11);

        #pragma unroll
        for (int j = 0; j < 4; j++) {
            uint16_t t[4];
            #pragma unroll
            for (int e = 0; e < 4; e++)
                t[e] = f2bf((a0[j]*ctx0[e] + a1[j]*ctx1[e]) * dc);
            *reinterpret_cast<uint64_t*>(
                &afrag[j*1024 + (hd>>1)*128 + l16*8 + (hd&1)*4]) =
                *reinterpret_cast<const uint64_t*>(t);
        }
    }
    __syncthreads();

    // ---- phase 5: hp MFMA + bias + shortcut -> s1 bf16 NHWC ----
    {
        const uint16_t* whp = (const uint16_t*)(wsw + WS_WHP);
        int nt = wave;
        f32x4 oacc[4];
        #pragma unroll
        for (int mt = 0; mt < 4; mt++) {
            int o0 = mt*16 + (l >> 4)*4;
            float4 hb = *reinterpret_cast<const float4*>(&hp_b[o0]);
            oacc[mt] = {hb.x, hb.y, hb.z, hb.w};
        }
        #pragma unroll
        for (int kb = 0; kb < 2; kb++) {
            short8 bf = *reinterpret_cast<const short8*>(&afrag[nt*1024 + kb*512 + 8*l]);
            #pragma unroll
            for (int mt = 0; mt < 4; mt++) {
                short8 a = *reinterpret_cast<const short8*>(&whp[mt*1024 + kb*512 + 8*l]);
                oacc[mt] = __builtin_amdgcn_mfma_f32_16x16x32_bf16(a, bf, oacc[mt], 0, 0, 0);
            }
        }
        int px = nt*16 + (l & 15);
        int yy = wy*8 + (px >> 3), xx = wx*8 + (px & 7);
        size_t pbase = ((size_t)b * HW + (size_t)yy * 512 + xx) * 64;
        #pragma unroll
        for (int mt = 0; mt < 4; mt++) {
            int o0 = mt*16 + (l >> 4)*4;
            uint64_t gg = *reinterpret_cast<const uint64_t*>(
                &gfrag[(px>>4)*1024 + (o0>>3)*128 + (px&15)*8 + (o0&7)]);
            uint16_t t[4];
            #pragma unroll
            for (int rr = 0; rr < 4; rr++) {
                float g = bf2f((uint16_t)(gg >> (16*rr)));
                t[rr] = f2bf(oacc[mt][rr] + g);
            }
            *reinterpret_cast<uint64_t*>(&s1out[pbase + o0]) =
                *reinterpret_cast<const uint64_t*>(t);
        }
    }
}

// Fused MLP: fc1 (MFMA) + GELU + dwconv3 + fc2 (MFMA) + residual.
// 16x8 tile, halo 18x10; s1 is bf16 NHWC. LDS 39KB.
__global__ __launch_bounds__(256, 3) void k3_mlp(
    const uint16_t* __restrict__ s1b, const float* __restrict__ wsw,
    float* __restrict__ out)
{
    __shared__ __align__(16) uint16_t sfrag[12288];  // [12 pt][1024]
    __shared__ __align__(16) uint16_t hbuf[7200];    // [10 hy][18 hx][40-pad ch]

    const float* f1b = wsw + WS_F1B;
    const float* f2b = wsw + WS_F2B;
    const float* dwp = wsw + WS_DWP;
    const uint16_t* w1f = (const uint16_t*)(wsw + WS_W1F);
    const uint16_t* w2f = (const uint16_t*)(wsw + WS_W2F);

    int tid = threadIdx.x;
    int wave = tid >> 6, l = tid & 63;
    int X0 = blockIdx.x * 16, Y0 = blockIdx.y * 8;
    int b = blockIdx.z;

    // ---- phase 0: s1 halo (NHWC bf16) -> fragments, fully coalesced ----
    for (int i = tid; i < 1440; i += 256) {
        int px = i >> 3, g = i & 7;
        int hy = px / 18, hx = px - hy*18;
        int yy = Y0 - 1 + hy, xx = X0 - 1 + hx;
        uint4 q = {0u, 0u, 0u, 0u};
        if ((unsigned)yy < 512u && (unsigned)xx < 512u)
            q = *reinterpret_cast<const uint4*>(
                &s1b[((size_t)b*HW + (size_t)yy*512 + xx)*64 + g*8]);
        *reinterpret_cast<uint4*>(&sfrag[(px>>4)*1024 + g*128 + (px&15)*8]) = q;
    }

    f32x4 acc[2][4];
    #pragma unroll
    for (int nt = 0; nt < 4; nt++) {
        float bias = f2b[nt*16 + (l & 15)];
        #pragma unroll
        for (int mi = 0; mi < 2; mi++) acc[mi][nt] = {bias, bias, bias, bias};
    }
    __syncthreads();

    for (int cc = 0; cc < 8; cc++) {
        // ---- fc1 (A = weights, B = pixels) + GELU -> hbuf ----
        short8 wA[2][2];
        #pragma unroll
        for (int mtw = 0; mtw < 2; mtw++)
            #pragma unroll
            for (int kb = 0; kb < 2; kb++)
                wA[mtw][kb] = *reinterpret_cast<const short8*>(
                    &w1f[(cc*2 + mtw)*1024 + kb*512 + 8*l]);
        float4 hb0 = *reinterpret_cast<const float4*>(&f1b[cc*32      + (l>>4)*4]);
        float4 hb1 = *reinterpret_cast<const float4*>(&f1b[cc*32 + 16 + (l>>4)*4]);

        for (int pt = wave; pt < 12; pt += 4) {
            f32x4 h0 = {hb0.x, hb0.y, hb0.z, hb0.w};
            f32x4 h1 = {hb1.x, hb1.y, hb1.z, hb1.w};
            #pragma unroll
            for (int kb = 0; kb < 2; kb++) {
                short8 bf = *reinterpret_cast<const short8*>(&sfrag[pt*1024 + kb*512 + 8*l]);
                h0 = __builtin_amdgcn_mfma_f32_16x16x32_bf16(wA[0][kb], bf, h0, 0, 0, 0);
                h1 = __builtin_amdgcn_mfma_f32_16x16x32_bf16(wA[1][kb], bf, h1, 0, 0, 0);
            }
            int px = pt*16 + (l & 15);
            if (px < 180) {
                int hy = px / 18, hx = px - hy*18;
                bool img = ((unsigned)(Y0-1+hy) < 512u) && ((unsigned)(X0-1+hx) < 512u);
                uint64_t v0 = 0, v1 = 0;
                if (img) {
                    uint16_t t0[4], t1[4];
                    #pragma unroll
                    for (int rr = 0; rr < 4; rr++) {
                        t0[rr] = f2bf(gelu_f(h0[rr]));
                        t1[rr] = f2bf(gelu_f(h1[rr]));
                    }
                    v0 = *reinterpret_cast<const uint64_t*>(t0);
                    v1 = *reinterpret_cast<const uint64_t*>(t1);
                }
                int base = (hy*18 + hx)*40 + (l>>4)*4;
                *reinterpret_cast<uint64_t*>(&hbuf[base])      = v0;
                *reinterpret_cast<uint64_t*>(&hbuf[base + 16]) = v1;
            }
        }
        __syncthreads();

        // ---- dwconv (per-tap) + fc2 MFMA ----
        short8 bfr[4];
        #pragma unroll
        for (int nt = 0; nt < 4; nt++)
            bfr[nt] = *reinterpret_cast<const short8*>(&w2f[nt*4096 + cc*512 + 8*l]);

        int hxl = l & 15, cg = l >> 4;
        uint4 R[4][3];
        #pragma unroll
        for (int tr = 0; tr < 4; tr++)
            #pragma unroll
            for (int dx = 0; dx < 3; dx++)
                R[tr][dx] = *reinterpret_cast<const uint4*>(
                    &hbuf[((wave*2 + tr)*18 + hxl + dx)*40 + cg*8]);

        float t[2][8];
        #pragma unroll
        for (int mi = 0; mi < 2; mi++)
            #pragma unroll
            for (int j = 0; j < 8; j++) t[mi][j] = 0.f;

        #pragma unroll
        for (int dy = 0; dy < 3; dy++) {
            #pragma unroll
            for (int dx = 0; dx < 3; dx++) {
                const float* wp = &dwp[(dy*3+dx)*256 + cc*32 + cg*8];
                float4 dwa = *reinterpret_cast<const float4*>(wp);
                float4 dwb = *reinterpret_cast<const float4*>(wp + 4);
                #pragma unroll
                for (int mi = 0; mi < 2; mi++) {
                    uint4 q = R[mi + dy][dx];
                    t[mi][0] += __uint_as_float(q.x << 16)         * dwa.x;
                    t[mi][1] += __uint_as_float(q.x & 0xffff0000u) * dwa.y;
                    t[mi][2] += __uint_as_float(q.y << 16)         * dwa.z;
                    t[mi][3] += __uint_as_float(q.y & 0xffff0000u) * dwa.w;
                    t[mi][4] += __uint_as_float(q.z << 16)         * dwb.x;
                    t[mi][5] += __uint_as_float(q.z & 0xffff0000u) * dwb.y;
                    t[mi][6] += __uint_as_float(q.w << 16)         * dwb.z;
                    t[mi][7] += __uint_as_float(q.w & 0xffff0000u) * dwb.w;
                }
            }
        }
        #pragma unroll
        for (int mi = 0; mi < 2; mi++) {
            short8 af;
            #pragma unroll
            for (int j = 0; j < 8; j++) af[j] = (short)f2bf(t[mi][j]);
            #pragma unroll
            for (int nt = 0; nt < 4; nt++)
                acc[mi][nt] = __builtin_amdgcn_mfma_f32_16x16x32_bf16(af, bfr[nt], acc[mi][nt], 0, 0, 0);
        }
        __syncthreads();
    }

    // ---- epilogue: + residual (bf16 NHWC s1) -> out (f32 NCHW) ----
    int r0 = (l >> 4) * 4;
    #pragma unroll
    for (int mi = 0; mi < 2; mi++) {
        int yrow = Y0 + wave*2 + mi;
        size_t srow = ((size_t)b*HW + (size_t)yrow*512 + X0 + r0) * 64;
        #pragma unroll
        for (int nt = 0; nt < 4; nt++) {
            int o = nt*16 + (l & 15);
            size_t oidx = ((size_t)b*CH + o)*HW + (size_t)yrow*512 + X0 + r0;
            float4 ov;
            ov.x = acc[mi][nt][0] + bf2f(s1b[srow + o]);
            ov.y = acc[mi][nt][1] + bf2f(s1b[srow + 64 + o]);
            ov.z = acc[mi][nt][2] + bf2f(s1b[srow + 128 + o]);
            ov.w = acc[mi][nt][3] + bf2f(s1b[srow + 192 + o]);
            *reinterpret_cast<float4*>(out + oidx) = ov;
        }
    }
}

extern "C" void kernel_launch(void* const* d_in, const int* in_sizes, int n_in,
                              void* d_out, int out_size, void* d_ws, size_t ws_size,
                              hipStream_t stream) {
    const float* x     = (const float*)d_in[0];
    const float* pa_w  = (const float*)d_in[1];
    const float* pa_b  = (const float*)d_in[2];
    const float* bn1_g = (const float*)d_in[3];
    const float* bn1_b = (const float*)d_in[4];
    const float* bn1_m = (const float*)d_in[5];
    const float* bn1_v = (const float*)d_in[6];
    const float* q_w   = (const float*)d_in[7];
    const float* q_b   = (const float*)d_in[8];
    const float* k_w   = (const float*)d_in[9];
    const float* k_b   = (const float*)d_in[10];
    const float* v_w   = (const float*)d_in[11];
    const float* v_b   = (const float*)d_in[12];
    const float* hp_w  = (const float*)d_in[13];
    const float* hp_b  = (const float*)d_in[14];
    const float* bn2_g = (const float*)d_in[15];
    const float* bn2_b = (const float*)d_in[16];
    const float* bn2_m = (const float*)d_in[17];
    const float* bn2_v = (const float*)d_in[18];
    const float* fc1_w = (const float*)d_in[19];
    const float* fc1_b = (const float*)d_in[20];
    const float* dw_w  = (const float*)d_in[21];
    const float* dw_b  = (const float*)d_in[22];
    const float* bn3_g = (const float*)d_in[23];
    const float* bn3_b = (const float*)d_in[24];
    const float* bn3_m = (const float*)d_in[25];
    const float* bn3_v = (const float*)d_in[26];
    const float* fc2_w = (const float*)d_in[27];
    const float* fc2_b = (const float*)d_in[28];

    uint16_t* s1b = (uint16_t*)d_ws;                                 // 67,108,864 B
    float*    wsw = (float*)((char*)d_ws + 134217728 + 268435456);   // ~105 KB

    k0_fold<<<dim3(1), dim3(256), 0, stream>>>(
        q_w, q_b, k_w, k_b, v_w, v_b,
        bn1_g, bn1_b, bn1_m, bn1_v,
        fc1_w, fc1_b, bn2_g, bn2_b, bn2_m, bn2_v,
        fc2_w, fc2_b, hp_w, dw_w, dw_b, bn3_g, bn3_b, bn3_m, bn3_v, wsw);

    k2_attn<<<dim3(8192), dim3(256), 0, stream>>>(
        x, pa_w, pa_b, hp_b, wsw, s1b);

    k3_mlp<<<dim3(32, 64, 2), dim3(256), 0, stream>>>(
        s1b, wsw, (float*)d_out);
}